// Round 1
// baseline (405.249 us; speedup 1.0000x reference)
//
#include <hip/hip_runtime.h>
#include <hip/hip_bf16.h>
#include <math.h>

// B=2 QL=512 KL=8192 D=1024 H=8 HD=128
typedef __attribute__((ext_vector_type(4))) float fx4;
typedef __attribute__((ext_vector_type(4))) short sx4;
typedef __attribute__((ext_vector_type(8))) short sx8;
typedef unsigned long long u64;

#define MFMA16(a, b, c) __builtin_amdgcn_mfma_f32_16x16x16bf16_1k(a, b, c, 0, 0, 0)
#define MFMA32(a, b, c) __builtin_amdgcn_mfma_f32_16x16x32_bf16(a, b, c, 0, 0, 0)

__device__ __forceinline__ unsigned short f2bf(float f) {
  unsigned int u = __float_as_uint(f);
  return (unsigned short)((u + 0x7fffu + ((u >> 16) & 1u)) >> 16);  // RNE
}

// packed f32x2 -> bf16x2 (RNE), gfx950 has no builtin for this
__device__ __forceinline__ unsigned cvtpk(float lo, float hi) {
  unsigned r;
  asm("v_cvt_pk_bf16_f32 %0, %1, %2" : "=v"(r) : "v"(lo), "v"(hi));
  return r;
}

// async global->LDS, 16B per lane; LDS dest is wave-uniform base + lane*16
typedef const __attribute__((address_space(1))) char* gc1p;
typedef __attribute__((address_space(3))) char* lc3p;
__device__ __forceinline__ void glds16(const void* g, const void* lds_uniform) {
  gc1p gp = (gc1p)(unsigned long long)(uintptr_t)g;
  lc3p lp = (lc3p)(unsigned)__builtin_amdgcn_readfirstlane((int)(unsigned)(uintptr_t)lds_uniform);
  __builtin_amdgcn_global_load_lds(gp, lp, 16, 0, 0);
}

// ---------------- prep (slim): weights f32->bf16 + mask pack ----------------
// [0,2048): Wq,Wk,Wv,Wf (512 blocks each)
// [2048,10240): mask pack
__global__ __launch_bounds__(256) void k_prep(
    const float* __restrict__ Wq, const float* __restrict__ Wk,
    const float* __restrict__ Wv, const float* __restrict__ Wf,
    const int* __restrict__ mask, short* cwq, short* cwk, short* cwv,
    short* cwf, u64* __restrict__ mb) {
  __shared__ unsigned char nib[256];
  const int bx = blockIdx.x;
  const int t = threadIdx.x;
  if (bx >= 2048) {  // mask pack: 16B/lane loads, nibble assembly via LDS
    const int mbx = bx - 2048;
    const int4 m = *(const int4*)(mask + (size_t)mbx * 1024 + t * 4);
    nib[t] = (unsigned char)((m.x != 0) | ((m.y != 0) << 1) | ((m.z != 0) << 2) |
                             ((m.w != 0) << 3));
    __syncthreads();
    if (t < 16) {
      u64 wv = 0;
#pragma unroll
      for (int i = 0; i < 16; i++) wv |= (u64)(nib[t * 16 + i] & 0xF) << (4 * i);
      mb[(size_t)mbx * 16 + t] = wv;
    }
    return;
  }
  const int seg = bx >> 9;
  const float* s = seg == 0 ? Wq : seg == 1 ? Wk : seg == 2 ? Wv : Wf;
  short* d = seg == 0 ? cwq : seg == 1 ? cwk : seg == 2 ? cwv : cwf;
  size_t i = (size_t)(bx & 511) * 2048 + (size_t)t * 8;
  const fx4 a = *(const fx4*)(s + i);
  const fx4 b = *(const fx4*)(s + i + 4);
  sx8 o;
  o[0] = (short)f2bf(a[0]); o[1] = (short)f2bf(a[1]);
  o[2] = (short)f2bf(a[2]); o[3] = (short)f2bf(a[3]);
  o[4] = (short)f2bf(b[0]); o[5] = (short)f2bf(b[1]);
  o[6] = (short)f2bf(b[2]); o[7] = (short)f2bf(b[3]);
  *(sx8*)(d + i) = o;
}

// ---------------- GEMM body: C = alpha*(A[M,K] @ B[N,K]^T + bias) ------------
// MODE 0: bf16 row-major C.  MODE 1: f32 row-major C.
// MODE 2: bf16 V^T output Vt[b][d][kl] with 8B-half swap when (d&8).
// MT: 128 (4 waves 2x2, acc 4x4) or 64 (4 waves 1x4, acc 4x2).
// AF32: A is f32 -> reg-stage (load f32x8 early, cvt_pk, swizzled ds_write);
//       else A is bf16 via global_load_lds w16. Same swizzled LDS layout.
// BK=64, XOR-swizzled LDS, MFMA 16x16x32.
// M>=8192: XCD swizzle — all 8 n-tiles of an A m-strip share bx%8 (one XCD).
template <int MODE, int MT, int AF32>
__device__ __forceinline__ void gemm_body(short* sA, short* sB,
                                          const void* __restrict__ Aptr,
                                          const short* __restrict__ Bw,
                                          const float* __restrict__ bias,
                                          void* __restrict__ Cptr, int M, int N,
                                          int K, float alpha, int bx) {
  const int t = threadIdx.x;
  const int lane = t & 63;
  const int w = t >> 6;
  const int quad = lane >> 4;
  const int l16 = lane & 15;
  const int x7 = l16 & 7;
  int m0, n0;
  if (M >= 8192) {
    const int ml = bx & 7, nn = (bx >> 3) & 7, mh = bx >> 6;
    m0 = (mh * 8 + ml) * MT;
    n0 = nn << 7;
  } else {
    const int ntile = N >> 7;
    n0 = (bx % ntile) << 7;
    m0 = (bx / ntile) * MT;
  }
  constexpr int NI = (MT == 128) ? 4 : 2;
  constexpr int NJ = (MT == 128) ? 4 : 2;
  const int wm = (MT == 128) ? ((w >> 1) << 6) : 0;
  const int wn = (MT == 128) ? ((w & 1) << 6) : (w << 5);
  const fx4 fzero = {0.f, 0.f, 0.f, 0.f};
  fx4 acc[4][NI];
#pragma unroll
  for (int i = 0; i < 4; i++)
#pragma unroll
    for (int j = 0; j < NI; j++) acc[i][j] = fzero;

  const int srow = lane >> 3;
  const int scb = lane & 7;

  for (int k0 = 0; k0 < K; k0 += 64) {
    fx4 ra[NJ][2];
    if (AF32) {
      // issue f32 A loads BEFORE the barrier: latency hides under barrier wait
      const float* Af = (const float*)Aptr;
#pragma unroll
      for (int j = 0; j < NJ; j++) {
        const int rbase = (MT == 128) ? (w * 32 + j * 8) : (j * 32 + w * 8);
        const int row = rbase + srow;
        const int cb = scb ^ (row & 7);
        const float* src = Af + (size_t)(m0 + row) * K + k0 + cb * 8;
        ra[j][0] = *(const fx4*)src;
        ra[j][1] = *(const fx4*)(src + 4);
      }
    }
    __syncthreads();
    if (!AF32) {
      const short* A = (const short*)Aptr;
#pragma unroll
      for (int j = 0; j < NJ; j++) {
        const int rbase = (MT == 128) ? (w * 32 + j * 8) : (j * 32 + w * 8);
        const int row = rbase + srow;
        const int cb = scb ^ (row & 7);
        glds16(A + (size_t)(m0 + row) * K + k0 + cb * 8, &sA[rbase * 64]);
      }
    }
#pragma unroll
    for (int j = 0; j < 4; j++) {
      const int row = w * 32 + j * 8 + srow;
      const int cb = scb ^ (row & 7);
      glds16(Bw + (size_t)(n0 + row) * K + k0 + cb * 8, &sB[(w * 32 + j * 8) * 64]);
    }
    if (AF32) {
      // cvt + write to the same swizzled slot glds16 would use: base + lane*16B
#pragma unroll
      for (int j = 0; j < NJ; j++) {
        const int rbase = (MT == 128) ? (w * 32 + j * 8) : (j * 32 + w * 8);
        sx8 o;
        unsigned* ou = (unsigned*)&o;
        ou[0] = cvtpk(ra[j][0][0], ra[j][0][1]);
        ou[1] = cvtpk(ra[j][0][2], ra[j][0][3]);
        ou[2] = cvtpk(ra[j][1][0], ra[j][1][1]);
        ou[3] = cvtpk(ra[j][1][2], ra[j][1][3]);
        *(sx8*)(&sA[rbase * 64 + lane * 8]) = o;
      }
    }
    __syncthreads();
#pragma unroll
    for (int kc = 0; kc < 2; kc++) {
      const int cbp = ((kc * 4 + quad) ^ x7) * 8;
      sx8 fa[4], fb[NI];
#pragma unroll
      for (int i = 0; i < 4; i++)
        fa[i] = *(const sx8*)(&sA[(wm + i * 16 + l16) * 64 + cbp]);
#pragma unroll
      for (int i = 0; i < NI; i++)
        fb[i] = *(const sx8*)(&sB[(wn + i * 16 + l16) * 64 + cbp]);
#pragma unroll
      for (int mi = 0; mi < 4; mi++)
#pragma unroll
        for (int ni = 0; ni < NI; ni++)
          acc[mi][ni] = MFMA32(fa[mi], fb[ni], acc[mi][ni]);
    }
  }
  // epilogue: C/D layout col=lane&15, row=quad*4+reg
#pragma unroll
  for (int ni = 0; ni < NI; ni++) {
    const int col = n0 + wn + ni * 16 + l16;
    const float bval = bias[col];
    if (MODE == 2) {
#pragma unroll
      for (int mi = 0; mi < 4; mi++) {
        const int rowb = m0 + wm + mi * 16 + quad * 4;
        const int bb = rowb >> 13;
        const int kl = (rowb & 8191) ^ ((col & 8) ? 4 : 0);
        sx4 pkv;
#pragma unroll
        for (int r = 0; r < 4; r++) pkv[r] = (short)f2bf(acc[mi][ni][r] + bval);
        *(sx4*)((unsigned short*)Cptr + ((size_t)bb * 1024 + col) * 8192 + kl) = pkv;
      }
    } else {
#pragma unroll
      for (int mi = 0; mi < 4; mi++)
#pragma unroll
        for (int r = 0; r < 4; r++) {
          const int row = m0 + wm + mi * 16 + quad * 4 + r;
          const float v = (acc[mi][ni][r] + bval) * alpha;
          if (MODE == 1) ((float*)Cptr)[(size_t)row * N + col] = v;
          else ((unsigned short*)Cptr)[(size_t)row * N + col] = f2bf(v);
        }
    }
  }
}

// K-projection (A = f32 ink): grid 1024
__global__ __launch_bounds__(256) void k_gemm_k(const float* __restrict__ ink,
                                                const short* __restrict__ cwk,
                                                const float* __restrict__ bk,
                                                short* __restrict__ Kp) {
  __shared__ __align__(16) short smem[16384];
  gemm_body<0, 128, 1>(smem, smem + 8192, ink, cwk, bk, Kp, 16384, 1024, 1024,
                       1.f, blockIdx.x);
}

// V-projection (fused transpose, A = f32 inv) + Q-projection (A = f32 inq)
__global__ __launch_bounds__(256) void k_proj_vq(
    const float* __restrict__ inv, const short* __restrict__ cwv,
    const float* __restrict__ bv, short* __restrict__ Vt,
    const float* __restrict__ inq, const short* __restrict__ cwq,
    const float* __restrict__ bq, short* __restrict__ Qp, float alpha_q) {
  __shared__ __align__(16) short smem[16384];
  const int bx = blockIdx.x;
  if (bx < 128)
    gemm_body<0, 64, 1>(smem, smem + 8192, inq, cwq, bq, Qp, 1024, 1024, 1024,
                        alpha_q, bx);
  else
    gemm_body<2, 128, 1>(smem, smem + 8192, inv, cwv, bv, Vt, 16384, 1024, 1024,
                         1.f, bx - 128);
}

// out-projection (A = bf16 summed): grid 128
__global__ __launch_bounds__(256) void k_gemm_out(const short* __restrict__ summed,
                                                  const short* __restrict__ cwf,
                                                  const float* __restrict__ bf,
                                                  float* __restrict__ out) {
  __shared__ __align__(16) short smem[16384];
  gemm_body<1, 64, 0>(smem, smem + 8192, summed, cwf, bf, out, 1024, 1024, 1024,
                      1.f, blockIdx.x);
}

// ---------------- flash attention (S^T trick, no-max softmax) ----------------
// grid 1024, XCD-swizzled: x = (g&7) + 8*(qt + 8*(g>>3)), g=(b*8+h)*8+s.
__global__ __launch_bounds__(256, 4) void k_attn(const short* __restrict__ Qp,
                                                 const short* __restrict__ Kp,
                                                 const short* __restrict__ Vt,
                                                 const u64* __restrict__ mb,
                                                 float* __restrict__ ml,
                                                 float* __restrict__ Op) {
  __shared__ __align__(16) short sK[8192];  // 64 keys x 128 d (256B rows, swizzled)
  __shared__ __align__(16) short sV[8192];  // 128 d x 64 keys (128B rows, swizzled)
  const int x = blockIdx.x;
  const int gl = x & 7;
  const int qt = (x >> 3) & 7;
  const int gh = x >> 6;
  const int g = gh * 8 + gl;  // 0..127
  const int s = g & 7;
  const int h = (g >> 3) & 7;
  const int b = g >> 6;
  const int li = ((b * 8 + h) * 8 + qt) * 8 + s;  // logical index for ml/Op
  const int t = threadIdx.x;
  const int lane = t & 63;
  const int w = t >> 6;
  const int quad = lane >> 4;
  const int l16 = lane & 15;
  const int x7 = l16 & 7;
  const int q0 = qt << 6;
  const fx4 fzero = {0.f, 0.f, 0.f, 0.f};

  const short* qbase = Qp + (size_t)(b * 512 + q0 + w * 16 + l16) * 1024 + h * 128;
  sx8 aq[4];
#pragma unroll
  for (int kc = 0; kc < 4; kc++) aq[kc] = *(const sx8*)(qbase + kc * 32 + quad * 8);

  fx4 Ot[8];
#pragma unroll
  for (int d = 0; d < 8; d++) Ot[d] = fzero;
  float lsum = 0.f;

  const short* kbase = Kp + (size_t)(b * 8192 + s * 1024) * 1024 + h * 128;
  const short* vbase = Vt + (size_t)(b * 1024 + h * 128) * 8192 + s * 1024;
  const u64* wdp = mb + (size_t)(b * 512 + q0 + w * 16 + l16) * 128 + s * 16;
  const int srow4 = lane >> 4, scb16 = lane & 15;
  const int srow8 = lane >> 3, scb8 = lane & 7;
  const int h4 = ((quad & 1) ^ ((l16 >> 3) & 1)) * 4;  // 8B-half parity (bank spread)

  for (int kt = 0; kt < 16; kt++) {
    __syncthreads();
#pragma unroll
    for (int j = 0; j < 4; j++) {  // K tile: 4 rows/issue
      const int row = (w * 4 + j) * 4 + srow4;
      const int cb = scb16 ^ (row & 7);
      glds16(kbase + (size_t)(kt * 64 + row) * 1024 + cb * 8, &sK[(w * 4 + j) * 512]);
    }
#pragma unroll
    for (int j = 0; j < 4; j++) {  // V^T tile: 8 rows/issue
      const int row = (w * 4 + j) * 8 + srow8;
      const int cb = scb8 ^ (row & 7);
      glds16(vbase + (size_t)row * 8192 + kt * 64 + cb * 8, &sV[(w * 4 + j) * 512]);
    }
    const u64 wd = wdp[kt];
    __syncthreads();
    const unsigned lo = (unsigned)wd, hi = (unsigned)(wd >> 32);
    sx4 pk[4];
#pragma unroll
    for (int nt = 0; nt < 4; nt++) {
      fx4 a = fzero;
#pragma unroll
      for (int kc = 0; kc < 4; kc++) {
        const sx8 kf = *(const sx8*)(&sK[(nt * 16 + l16) * 128 + ((kc * 4 + quad) ^ x7) * 8]);
        a = MFMA32(kf, aq[kc], a);  // S^T: row=key, col=q
      }
      const unsigned bits = (nt & 2) ? hi : lo;
      const int sh = (nt & 1) * 16 + quad * 4;
      float pv[4];
#pragma unroll
      for (int r = 0; r < 4; r++) {
        const float e = __builtin_amdgcn_exp2f(a[r]);  // scale*log2e folded into Qp
        pv[r] = ((bits >> (sh + r)) & 1u) ? e : 0.f;
        lsum += pv[r];
      }
      sx4 pko;
      ((unsigned*)&pko)[0] = __builtin_amdgcn_perm(
          __float_as_uint(pv[1]) + 0x8000u, __float_as_uint(pv[0]) + 0x8000u, 0x07060302u);
      ((unsigned*)&pko)[1] = __builtin_amdgcn_perm(
          __float_as_uint(pv[3]) + 0x8000u, __float_as_uint(pv[2]) + 0x8000u, 0x07060302u);
      pk[nt] = pko;
    }
#pragma unroll
    for (int dt = 0; dt < 8; dt++) {
      fx4 o = Ot[dt];
#pragma unroll
      for (int nt = 0; nt < 4; nt++) {
        const int cb = (2 * nt + (quad >> 1)) ^ x7;
        const sx4 vf = *(const sx4*)(&sV[(dt * 16 + l16) * 64 + cb * 8 + h4]);
        o = MFMA16(vf, pk[nt], o);  // O^T: row=d, col=q
      }
      Ot[dt] = o;
    }
  }
  lsum += __shfl_xor(lsum, 16, 64);
  lsum += __shfl_xor(lsum, 32, 64);
  if (lane < 16) ml[(size_t)li * 64 + w * 16 + l16] = lsum;
  float* ob = Op + (size_t)li * 8192 + (w * 16 + l16) * 128 + quad * 4;
#pragma unroll
  for (int dt = 0; dt < 8; dt++) *(fx4*)(ob + dt * 16) = Ot[dt];
}

// ---------------- combine 8 KL-split partials -> summed bf16 -----------------
__global__ __launch_bounds__(256) void k_combine(const float* __restrict__ ml,
                                                 const float* __restrict__ Op,
                                                 short* __restrict__ summed) {
  const int xc = blockIdx.x;  // qt + 8*h + 64*b
  const int qt = xc & 7;
  const int h = (xc >> 3) & 7;
  const int b = xc >> 6;
  const int t = threadIdx.x;
  const int row = t >> 2;
  const int dg = (t & 3) * 32;
  float L = 0.f;
#pragma unroll
  for (int s = 0; s < 8; s++) L += ml[(size_t)(xc * 8 + s) * 64 + row];
  float o[32];
#pragma unroll
  for (int i = 0; i < 32; i++) o[i] = 0.f;
  if (L != 0.f) {
#pragma unroll
    for (int s = 0; s < 8; s++) {
      const float* src = Op + (size_t)(xc * 8 + s) * 8192 + row * 128 + dg;
#pragma unroll
      for (int i = 0; i < 8; i++) {
        const fx4 v = *(const fx4*)(src + i * 4);
        o[i * 4 + 0] += v[0]; o[i * 4 + 1] += v[1];
        o[i * 4 + 2] += v[2]; o[i * 4 + 3] += v[3];
      }
    }
    const float inv = 1.f / L;
#pragma unroll
    for (int i = 0; i < 32; i++) o[i] *= inv;
  }
  short* dst = summed + (size_t)(b * 512 + qt * 64 + row) * 1024 + h * 128 + dg;
#pragma unroll
  for (int i = 0; i < 4; i++) {
    sx8 pkv;
#pragma unroll
    for (int j = 0; j < 8; j++) pkv[j] = (short)f2bf(o[i * 8 + j]);
    *(sx8*)(dst + i * 8) = pkv;
  }
}

// ---------------- host ------------------------------------------------------
extern "C" void kernel_launch(void* const* d_in, const int* in_sizes, int n_in,
                              void* d_out, int out_size, void* d_ws, size_t ws_size,
                              hipStream_t stream) {
  (void)in_sizes; (void)n_in; (void)out_size; (void)ws_size;
  const float* inq = (const float*)d_in[0];
  const float* ink = (const float*)d_in[1];
  const float* inv = (const float*)d_in[2];
  const int* mask = (const int*)d_in[3];
  const float* Wq = (const float*)d_in[4];
  const float* bq = (const float*)d_in[5];
  const float* Wk = (const float*)d_in[6];
  const float* bk = (const float*)d_in[7];
  const float* Wv = (const float*)d_in[8];
  const float* bv = (const float*)d_in[9];
  const float* Wf = (const float*)d_in[10];
  const float* bf = (const float*)d_in[11];

  char* ws = (char*)d_ws;
  short* Vt = (short*)(ws + 0);            // 33.5MB bf16
  short* Kp = (short*)(ws + 33554432);     // 33.5MB bf16
  float* Op = (float*)(ws + 67108864);     // 33.5MB f32 attn partials
  short* cwq = (short*)(ws + 102760448);   // 2MB each
  short* cwk = (short*)(ws + 104857600);
  short* cwv = (short*)(ws + 106954752);
  short* cwf = (short*)(ws + 109051904);
  short* Qp = (short*)(ws + 111149056);
  short* summed = (short*)(ws + 113246208);
  u64* mb = (u64*)(ws + 115343360);
  float* ml = (float*)(ws + 116391936);

  const float alpha_q = 0.12751757f;  // (1/sqrt(128)) * log2(e)

  k_prep<<<10240, 256, 0, stream>>>(Wq, Wk, Wv, Wf, mask, cwq, cwk, cwv, cwf, mb);
  k_gemm_k<<<1024, 256, 0, stream>>>(ink, cwk, bk, Kp);
  k_proj_vq<<<1152, 256, 0, stream>>>(inv, cwv, bv, Vt, inq, cwq, bq, Qp, alpha_q);
  k_attn<<<1024, 256, 0, stream>>>(Qp, Kp, Vt, mb, ml, Op);
  k_combine<<<128, 256, 0, stream>>>(ml, Op, summed);
  k_gemm_out<<<128, 256, 0, stream>>>(summed, cwf, bf, (float*)d_out);
}

// Round 2
// 392.941 us; speedup vs baseline: 1.0313x; 1.0313x over previous
//
#include <hip/hip_runtime.h>
#include <hip/hip_bf16.h>
#include <math.h>

// B=2 QL=512 KL=8192 D=1024 H=8 HD=128
typedef __attribute__((ext_vector_type(4))) float fx4;
typedef __attribute__((ext_vector_type(4))) short sx4;
typedef __attribute__((ext_vector_type(8))) short sx8;
typedef unsigned long long u64;

#define MFMA16(a, b, c) __builtin_amdgcn_mfma_f32_16x16x16bf16_1k(a, b, c, 0, 0, 0)
#define MFMA32(a, b, c) __builtin_amdgcn_mfma_f32_16x16x32_bf16(a, b, c, 0, 0, 0)

__device__ __forceinline__ unsigned short f2bf(float f) {
  unsigned int u = __float_as_uint(f);
  return (unsigned short)((u + 0x7fffu + ((u >> 16) & 1u)) >> 16);  // RNE
}

// async global->LDS, 16B per lane; LDS dest is wave-uniform base + lane*16
typedef const __attribute__((address_space(1))) char* gc1p;
typedef __attribute__((address_space(3))) char* lc3p;
__device__ __forceinline__ void glds16(const void* g, const void* lds_uniform) {
  gc1p gp = (gc1p)(unsigned long long)(uintptr_t)g;
  lc3p lp = (lc3p)(unsigned)__builtin_amdgcn_readfirstlane((int)(unsigned)(uintptr_t)lds_uniform);
  __builtin_amdgcn_global_load_lds(gp, lp, 16, 0, 0);
}

// ---------------- prep: all f32->bf16 conversions + mask pack ----------------
// Latency-optimized: each convert block owns 16384 elems, 4-deep unrolled loop
// of 64B/lane loads (16 outstanding dwordx4/lane vs 2 in the old 1-shot form).
// [0,1024): ink -> ck     (16 elems/thread/iter, 4 iters)
// [1024,2048): inv -> cv
// [2048,2112): inq -> cq
// [2112,2368): Wq,Wk,Wv,Wf (64 blocks each)
// [2368,4416): mask pack, 4 rows/block
__global__ __launch_bounds__(256) void k_prep(
    const float* __restrict__ ink, const float* __restrict__ inv,
    const float* __restrict__ inq, const float* __restrict__ Wq,
    const float* __restrict__ Wk, const float* __restrict__ Wv,
    const float* __restrict__ Wf, const int* __restrict__ mask, short* ck,
    short* cv, short* cq, short* cwq, short* cwk, short* cwv, short* cwf,
    u64* __restrict__ mb) {
  __shared__ unsigned char nib[4][256];
  const int bx = blockIdx.x;
  const int t = threadIdx.x;
  if (bx >= 2368) {  // mask pack: 4 rows/block, 4 independent 16B loads/lane
    const int mrow0 = (bx - 2368) * 4;
#pragma unroll
    for (int j = 0; j < 4; j++) {
      const int4 m = *(const int4*)(mask + (size_t)(mrow0 + j) * 1024 + t * 4);
      nib[j][t] = (unsigned char)((m.x != 0) | ((m.y != 0) << 1) |
                                  ((m.z != 0) << 2) | ((m.w != 0) << 3));
    }
    __syncthreads();
    if (t < 64) {
      const int j = t >> 4, i = t & 15;
      u64 wv = 0;
#pragma unroll
      for (int k = 0; k < 16; k++)
        wv |= (u64)(nib[j][i * 16 + k] & 0xF) << (4 * k);
      mb[(size_t)(mrow0 + j) * 16 + i] = wv;
    }
    return;
  }
  const float* s;
  short* d;
  size_t base;
  if (bx < 1024) {
    s = ink; d = ck; base = (size_t)bx * 16384;
  } else if (bx < 2048) {
    s = inv; d = cv; base = (size_t)(bx - 1024) * 16384;
  } else if (bx < 2112) {
    s = inq; d = cq; base = (size_t)(bx - 2048) * 16384;
  } else {
    const int r = bx - 2112;
    const int seg = r >> 6;
    s = seg == 0 ? Wq : seg == 1 ? Wk : seg == 2 ? Wv : Wf;
    d = seg == 0 ? cwq : seg == 1 ? cwk : seg == 2 ? cwv : cwf;
    base = (size_t)(r & 63) * 16384;
  }
#pragma unroll
  for (int it = 0; it < 4; it++) {
    const size_t i = base + (size_t)it * 4096 + (size_t)t * 16;
    const fx4 a0 = *(const fx4*)(s + i);
    const fx4 a1 = *(const fx4*)(s + i + 4);
    const fx4 a2 = *(const fx4*)(s + i + 8);
    const fx4 a3 = *(const fx4*)(s + i + 12);
    sx8 o0, o1;
    o0[0] = (short)f2bf(a0[0]); o0[1] = (short)f2bf(a0[1]);
    o0[2] = (short)f2bf(a0[2]); o0[3] = (short)f2bf(a0[3]);
    o0[4] = (short)f2bf(a1[0]); o0[5] = (short)f2bf(a1[1]);
    o0[6] = (short)f2bf(a1[2]); o0[7] = (short)f2bf(a1[3]);
    o1[0] = (short)f2bf(a2[0]); o1[1] = (short)f2bf(a2[1]);
    o1[2] = (short)f2bf(a2[2]); o1[3] = (short)f2bf(a2[3]);
    o1[4] = (short)f2bf(a3[0]); o1[5] = (short)f2bf(a3[1]);
    o1[6] = (short)f2bf(a3[2]); o1[7] = (short)f2bf(a3[3]);
    *(sx8*)(d + i) = o0;
    *(sx8*)(d + i + 8) = o1;
  }
}

// ---------------- GEMM body: C = alpha*(A[M,K] @ B[N,K]^T + bias) ------------
// MODE 0: bf16 row-major C.  MODE 1: f32 row-major C.
// MODE 2: bf16 V^T output Vt[b][d][kl] with 8B-half swap when (d&8).
// MT: 128 (4 waves 2x2, acc 4x4) or 64 (4 waves 1x4, acc 4x2).
// bf16 A via global_load_lds w16, BK=64, XOR-swizzled LDS, MFMA 16x16x32.
// M>=8192: XCD swizzle — all 8 n-tiles of an A m-strip share bx%8 (one XCD).
template <int MODE, int MT>
__device__ __forceinline__ void gemm_body(short* sA, short* sB,
                                          const short* __restrict__ A,
                                          const short* __restrict__ Bw,
                                          const float* __restrict__ bias,
                                          void* __restrict__ Cptr, int M, int N,
                                          int K, float alpha, int bx) {
  const int t = threadIdx.x;
  const int lane = t & 63;
  const int w = t >> 6;
  const int quad = lane >> 4;
  const int l16 = lane & 15;
  const int x7 = l16 & 7;
  int m0, n0;
  if (M >= 8192) {
    const int ml = bx & 7, nn = (bx >> 3) & 7, mh = bx >> 6;
    m0 = (mh * 8 + ml) * MT;
    n0 = nn << 7;
  } else {
    const int ntile = N >> 7;
    n0 = (bx % ntile) << 7;
    m0 = (bx / ntile) * MT;
  }
  constexpr int NI = (MT == 128) ? 4 : 2;
  const int wm = (MT == 128) ? ((w >> 1) << 6) : 0;
  const int wn = (MT == 128) ? ((w & 1) << 6) : (w << 5);
  const fx4 fzero = {0.f, 0.f, 0.f, 0.f};
  fx4 acc[4][NI];
#pragma unroll
  for (int i = 0; i < 4; i++)
#pragma unroll
    for (int j = 0; j < NI; j++) acc[i][j] = fzero;

  const int srow = lane >> 3;
  const int scb = lane & 7;

  for (int k0 = 0; k0 < K; k0 += 64) {
    __syncthreads();
    if (MT == 128) {
#pragma unroll
      for (int j = 0; j < 4; j++) {
        const int row = w * 32 + j * 8 + srow;
        const int cb = scb ^ (row & 7);
        glds16(A + (size_t)(m0 + row) * K + k0 + cb * 8, &sA[(w * 32 + j * 8) * 64]);
      }
    } else {
#pragma unroll
      for (int j = 0; j < 2; j++) {
        const int row = j * 32 + w * 8 + srow;
        const int cb = scb ^ (row & 7);
        glds16(A + (size_t)(m0 + row) * K + k0 + cb * 8, &sA[(j * 32 + w * 8) * 64]);
      }
    }
#pragma unroll
    for (int j = 0; j < 4; j++) {
      const int row = w * 32 + j * 8 + srow;
      const int cb = scb ^ (row & 7);
      glds16(Bw + (size_t)(n0 + row) * K + k0 + cb * 8, &sB[(w * 32 + j * 8) * 64]);
    }
    __syncthreads();
#pragma unroll
    for (int kc = 0; kc < 2; kc++) {
      const int cbp = ((kc * 4 + quad) ^ x7) * 8;
      sx8 fa[4], fb[NI];
#pragma unroll
      for (int i = 0; i < 4; i++)
        fa[i] = *(const sx8*)(&sA[(wm + i * 16 + l16) * 64 + cbp]);
#pragma unroll
      for (int i = 0; i < NI; i++)
        fb[i] = *(const sx8*)(&sB[(wn + i * 16 + l16) * 64 + cbp]);
#pragma unroll
      for (int mi = 0; mi < 4; mi++)
#pragma unroll
        for (int ni = 0; ni < NI; ni++)
          acc[mi][ni] = MFMA32(fa[mi], fb[ni], acc[mi][ni]);
    }
  }
  // epilogue: C/D layout col=lane&15, row=quad*4+reg
#pragma unroll
  for (int ni = 0; ni < NI; ni++) {
    const int col = n0 + wn + ni * 16 + l16;
    const float bval = bias[col];
    if (MODE == 2) {
#pragma unroll
      for (int mi = 0; mi < 4; mi++) {
        const int rowb = m0 + wm + mi * 16 + quad * 4;
        const int bb = rowb >> 13;
        const int kl = (rowb & 8191) ^ ((col & 8) ? 4 : 0);
        sx4 pkv;
#pragma unroll
        for (int r = 0; r < 4; r++) pkv[r] = (short)f2bf(acc[mi][ni][r] + bval);
        *(sx4*)((unsigned short*)Cptr + ((size_t)bb * 1024 + col) * 8192 + kl) = pkv;
      }
    } else {
#pragma unroll
      for (int mi = 0; mi < 4; mi++)
#pragma unroll
        for (int r = 0; r < 4; r++) {
          const int row = m0 + wm + mi * 16 + quad * 4 + r;
          const float v = (acc[mi][ni][r] + bval) * alpha;
          if (MODE == 1) ((float*)Cptr)[(size_t)row * N + col] = v;
          else ((unsigned short*)Cptr)[(size_t)row * N + col] = f2bf(v);
        }
    }
  }
}

// K-projection: grid 1024
__global__ __launch_bounds__(256) void k_gemm_k(const short* __restrict__ ck,
                                                const short* __restrict__ cwk,
                                                const float* __restrict__ bk,
                                                short* __restrict__ Kp) {
  __shared__ __align__(16) short smem[16384];
  gemm_body<0, 128>(smem, smem + 8192, ck, cwk, bk, Kp, 16384, 1024, 1024, 1.f,
                    blockIdx.x);
}

// V-projection (fused transpose) + Q-projection: grid 128 + 1024
__global__ __launch_bounds__(256) void k_proj_vq(
    const short* __restrict__ cv, const short* __restrict__ cwv,
    const float* __restrict__ bv, short* __restrict__ Vt,
    const short* __restrict__ cq, const short* __restrict__ cwq,
    const float* __restrict__ bq, short* __restrict__ Qp, float alpha_q) {
  __shared__ __align__(16) short smem[16384];
  const int bx = blockIdx.x;
  if (bx < 128)
    gemm_body<0, 64>(smem, smem + 8192, cq, cwq, bq, Qp, 1024, 1024, 1024,
                     alpha_q, bx);
  else
    gemm_body<2, 128>(smem, smem + 8192, cv, cwv, bv, Vt, 16384, 1024, 1024,
                      1.f, bx - 128);
}

// out-projection: grid 128
__global__ __launch_bounds__(256) void k_gemm_out(const short* __restrict__ summed,
                                                  const short* __restrict__ cwf,
                                                  const float* __restrict__ bf,
                                                  float* __restrict__ out) {
  __shared__ __align__(16) short smem[16384];
  gemm_body<1, 64>(smem, smem + 8192, summed, cwf, bf, out, 1024, 1024, 1024,
                   1.f, blockIdx.x);
}

// ---------------- flash attention (S^T trick, no-max softmax) ----------------
// grid 1024, XCD-swizzled: x = (g&7) + 8*(qt + 8*(g>>3)), g=(b*8+h)*8+s.
__global__ __launch_bounds__(256, 4) void k_attn(const short* __restrict__ Qp,
                                                 const short* __restrict__ Kp,
                                                 const short* __restrict__ Vt,
                                                 const u64* __restrict__ mb,
                                                 float* __restrict__ ml,
                                                 float* __restrict__ Op) {
  __shared__ __align__(16) short sK[8192];  // 64 keys x 128 d (256B rows, swizzled)
  __shared__ __align__(16) short sV[8192];  // 128 d x 64 keys (128B rows, swizzled)
  const int x = blockIdx.x;
  const int gl = x & 7;
  const int qt = (x >> 3) & 7;
  const int gh = x >> 6;
  const int g = gh * 8 + gl;  // 0..127
  const int s = g & 7;
  const int h = (g >> 3) & 7;
  const int b = g >> 6;
  const int li = ((b * 8 + h) * 8 + qt) * 8 + s;  // logical index for ml/Op
  const int t = threadIdx.x;
  const int lane = t & 63;
  const int w = t >> 6;
  const int quad = lane >> 4;
  const int l16 = lane & 15;
  const int x7 = l16 & 7;
  const int q0 = qt << 6;
  const fx4 fzero = {0.f, 0.f, 0.f, 0.f};

  const short* qbase = Qp + (size_t)(b * 512 + q0 + w * 16 + l16) * 1024 + h * 128;
  sx8 aq[4];
#pragma unroll
  for (int kc = 0; kc < 4; kc++) aq[kc] = *(const sx8*)(qbase + kc * 32 + quad * 8);

  fx4 Ot[8];
#pragma unroll
  for (int d = 0; d < 8; d++) Ot[d] = fzero;
  float lsum = 0.f;

  const short* kbase = Kp + (size_t)(b * 8192 + s * 1024) * 1024 + h * 128;
  const short* vbase = Vt + (size_t)(b * 1024 + h * 128) * 8192 + s * 1024;
  const u64* wdp = mb + (size_t)(b * 512 + q0 + w * 16 + l16) * 128 + s * 16;
  const int srow4 = lane >> 4, scb16 = lane & 15;
  const int srow8 = lane >> 3, scb8 = lane & 7;
  const int h4 = ((quad & 1) ^ ((l16 >> 3) & 1)) * 4;  // 8B-half parity (bank spread)

  for (int kt = 0; kt < 16; kt++) {
    __syncthreads();
#pragma unroll
    for (int j = 0; j < 4; j++) {  // K tile: 4 rows/issue
      const int row = (w * 4 + j) * 4 + srow4;
      const int cb = scb16 ^ (row & 7);
      glds16(kbase + (size_t)(kt * 64 + row) * 1024 + cb * 8, &sK[(w * 4 + j) * 512]);
    }
#pragma unroll
    for (int j = 0; j < 4; j++) {  // V^T tile: 8 rows/issue
      const int row = (w * 4 + j) * 8 + srow8;
      const int cb = scb8 ^ (row & 7);
      glds16(vbase + (size_t)row * 8192 + kt * 64 + cb * 8, &sV[(w * 4 + j) * 512]);
    }
    const u64 wd = wdp[kt];
    __syncthreads();
    const unsigned lo = (unsigned)wd, hi = (unsigned)(wd >> 32);
    sx4 pk[4];
#pragma unroll
    for (int nt = 0; nt < 4; nt++) {
      fx4 a = fzero;
#pragma unroll
      for (int kc = 0; kc < 4; kc++) {
        const sx8 kf = *(const sx8*)(&sK[(nt * 16 + l16) * 128 + ((kc * 4 + quad) ^ x7) * 8]);
        a = MFMA32(kf, aq[kc], a);  // S^T: row=key, col=q
      }
      const unsigned bits = (nt & 2) ? hi : lo;
      const int sh = (nt & 1) * 16 + quad * 4;
      float pv[4];
#pragma unroll
      for (int r = 0; r < 4; r++) {
        const float e = __builtin_amdgcn_exp2f(a[r]);  // scale*log2e folded into Qp
        pv[r] = ((bits >> (sh + r)) & 1u) ? e : 0.f;
        lsum += pv[r];
      }
      sx4 pko;
      ((unsigned*)&pko)[0] = __builtin_amdgcn_perm(
          __float_as_uint(pv[1]) + 0x8000u, __float_as_uint(pv[0]) + 0x8000u, 0x07060302u);
      ((unsigned*)&pko)[1] = __builtin_amdgcn_perm(
          __float_as_uint(pv[3]) + 0x8000u, __float_as_uint(pv[2]) + 0x8000u, 0x07060302u);
      pk[nt] = pko;
    }
#pragma unroll
    for (int dt = 0; dt < 8; dt++) {
      fx4 o = Ot[dt];
#pragma unroll
      for (int nt = 0; nt < 4; nt++) {
        const int cb = (2 * nt + (quad >> 1)) ^ x7;
        const sx4 vf = *(const sx4*)(&sV[(dt * 16 + l16) * 64 + cb * 8 + h4]);
        o = MFMA16(vf, pk[nt], o);  // O^T: row=d, col=q
      }
      Ot[dt] = o;
    }
  }
  lsum += __shfl_xor(lsum, 16, 64);
  lsum += __shfl_xor(lsum, 32, 64);
  if (lane < 16) ml[(size_t)li * 64 + w * 16 + l16] = lsum;
  float* ob = Op + (size_t)li * 8192 + (w * 16 + l16) * 128 + quad * 4;
#pragma unroll
  for (int dt = 0; dt < 8; dt++) *(fx4*)(ob + dt * 16) = Ot[dt];
}

// ---------------- combine 8 KL-split partials -> summed bf16 -----------------
// grid 256: each block does one (b,h,qt) x one 64-wide d-half (full CU coverage)
__global__ __launch_bounds__(256) void k_combine(const float* __restrict__ ml,
                                                 const float* __restrict__ Op,
                                                 short* __restrict__ summed) {
  const int bx = blockIdx.x;
  const int xc = bx >> 1;        // qt + 8*h + 64*b
  const int dh = (bx & 1) * 64;  // d-half
  const int qt = xc & 7;
  const int h = (xc >> 3) & 7;
  const int b = xc >> 6;
  const int t = threadIdx.x;
  const int row = t >> 2;
  const int dg = dh + (t & 3) * 16;
  float L = 0.f;
#pragma unroll
  for (int s = 0; s < 8; s++) L += ml[(size_t)(xc * 8 + s) * 64 + row];
  float o[16];
#pragma unroll
  for (int i = 0; i < 16; i++) o[i] = 0.f;
  if (L != 0.f) {
#pragma unroll
    for (int s = 0; s < 8; s++) {
      const float* src = Op + (size_t)(xc * 8 + s) * 8192 + row * 128 + dg;
#pragma unroll
      for (int i = 0; i < 4; i++) {
        const fx4 v = *(const fx4*)(src + i * 4);
        o[i * 4 + 0] += v[0]; o[i * 4 + 1] += v[1];
        o[i * 4 + 2] += v[2]; o[i * 4 + 3] += v[3];
      }
    }
    const float inv = 1.f / L;
#pragma unroll
    for (int i = 0; i < 16; i++) o[i] *= inv;
  }
  short* dst = summed + (size_t)(b * 512 + qt * 64 + row) * 1024 + h * 128 + dg;
#pragma unroll
  for (int i = 0; i < 2; i++) {
    sx8 pkv;
#pragma unroll
    for (int j = 0; j < 8; j++) pkv[j] = (short)f2bf(o[i * 8 + j]);
    *(sx8*)(dst + i * 8) = pkv;
  }
}

// ---------------- host ------------------------------------------------------
extern "C" void kernel_launch(void* const* d_in, const int* in_sizes, int n_in,
                              void* d_out, int out_size, void* d_ws, size_t ws_size,
                              hipStream_t stream) {
  (void)in_sizes; (void)n_in; (void)out_size; (void)ws_size;
  const float* inq = (const float*)d_in[0];
  const float* ink = (const float*)d_in[1];
  const float* inv = (const float*)d_in[2];
  const int* mask = (const int*)d_in[3];
  const float* Wq = (const float*)d_in[4];
  const float* bq = (const float*)d_in[5];
  const float* Wk = (const float*)d_in[6];
  const float* bk = (const float*)d_in[7];
  const float* Wv = (const float*)d_in[8];
  const float* bv = (const float*)d_in[9];
  const float* Wf = (const float*)d_in[10];
  const float* bf = (const float*)d_in[11];

  char* ws = (char*)d_ws;
  short* S1 = (short*)(ws + 0);            // ck -> Vt : 33.5MB
  short* Kp = (short*)(ws + 33554432);     // 33.5MB bf16
  short* S3 = (short*)(ws + 67108864);     // cv -> Op(f32) : 33.5MB
  short* cq = (short*)(ws + 100663296);    // 2MB each
  short* cwq = (short*)(ws + 102760448);
  short* cwk = (short*)(ws + 104857600);
  short* cwv = (short*)(ws + 106954752);
  short* cwf = (short*)(ws + 109051904);
  short* Qp = (short*)(ws + 111149056);
  short* summed = (short*)(ws + 113246208);
  u64* mb = (u64*)(ws + 115343360);
  float* ml = (float*)(ws + 116391936);

  const float alpha_q = 0.12751757f;  // (1/sqrt(128)) * log2(e)

  k_prep<<<4416, 256, 0, stream>>>(ink, inv, inq, Wq, Wk, Wv, Wf, mask, S1, S3,
                                   cq, cwq, cwk, cwv, cwf, mb);
  k_gemm_k<<<1024, 256, 0, stream>>>(S1, cwk, bk, Kp);
  k_proj_vq<<<1152, 256, 0, stream>>>(S3, cwv, bv, S1, cq, cwq, bq, Qp, alpha_q);
  k_attn<<<1024, 256, 0, stream>>>(Qp, Kp, S1, mb, ml, (float*)S3);  // -> ml, Op
  k_combine<<<256, 256, 0, stream>>>(ml, (const float*)S3, summed);
  k_gemm_out<<<128, 256, 0, stream>>>(summed, cwf, bf, (float*)d_out);
}

// Round 3
// 387.073 us; speedup vs baseline: 1.0470x; 1.0152x over previous
//
#include <hip/hip_runtime.h>
#include <hip/hip_bf16.h>
#include <math.h>

// B=2 QL=512 KL=8192 D=1024 H=8 HD=128
typedef __attribute__((ext_vector_type(4))) float fx4;
typedef __attribute__((ext_vector_type(4))) short sx4;
typedef __attribute__((ext_vector_type(8))) short sx8;
typedef unsigned long long u64;

#define MFMA16(a, b, c) __builtin_amdgcn_mfma_f32_16x16x16bf16_1k(a, b, c, 0, 0, 0)
#define MFMA32(a, b, c) __builtin_amdgcn_mfma_f32_16x16x32_bf16(a, b, c, 0, 0, 0)

__device__ __forceinline__ unsigned short f2bf(float f) {
  unsigned int u = __float_as_uint(f);
  return (unsigned short)((u + 0x7fffu + ((u >> 16) & 1u)) >> 16);  // RNE
}

// packed f32x2 -> bf16x2 (RNE)
__device__ __forceinline__ unsigned cvtpk(float lo, float hi) {
  unsigned r;
  asm("v_cvt_pk_bf16_f32 %0, %1, %2" : "=v"(r) : "v"(lo), "v"(hi));
  return r;
}

// async global->LDS, 16B per lane; LDS dest is wave-uniform base + lane*16
typedef const __attribute__((address_space(1))) char* gc1p;
typedef __attribute__((address_space(3))) char* lc3p;
__device__ __forceinline__ void glds16(const void* g, const void* lds_uniform) {
  gc1p gp = (gc1p)(unsigned long long)(uintptr_t)g;
  lc3p lp = (lc3p)(unsigned)__builtin_amdgcn_readfirstlane((int)(unsigned)(uintptr_t)lds_uniform);
  __builtin_amdgcn_global_load_lds(gp, lp, 16, 0, 0);
}

// ---------------- prep (slim): weights f32->bf16 + mask pack ----------------
// [0,256): Wq,Wk,Wv,Wf (64 blocks each, 16384 elems/block)
// [256,2304): mask pack, 4 rows/block
__global__ __launch_bounds__(256) void k_prep(
    const float* __restrict__ Wq, const float* __restrict__ Wk,
    const float* __restrict__ Wv, const float* __restrict__ Wf,
    const int* __restrict__ mask, short* cwq, short* cwk, short* cwv,
    short* cwf, u64* __restrict__ mb) {
  __shared__ unsigned char nib[4][256];
  const int bx = blockIdx.x;
  const int t = threadIdx.x;
  if (bx >= 256) {  // mask pack: 4 rows/block, 4 independent 16B loads/lane
    const int mrow0 = (bx - 256) * 4;
#pragma unroll
    for (int j = 0; j < 4; j++) {
      const int4 m = *(const int4*)(mask + (size_t)(mrow0 + j) * 1024 + t * 4);
      nib[j][t] = (unsigned char)((m.x != 0) | ((m.y != 0) << 1) |
                                  ((m.z != 0) << 2) | ((m.w != 0) << 3));
    }
    __syncthreads();
    if (t < 64) {
      const int j = t >> 4, i = t & 15;
      u64 wv = 0;
#pragma unroll
      for (int k = 0; k < 16; k++)
        wv |= (u64)(nib[j][i * 16 + k] & 0xF) << (4 * k);
      mb[(size_t)(mrow0 + j) * 16 + i] = wv;
    }
    return;
  }
  const int seg = bx >> 6;
  const float* s = seg == 0 ? Wq : seg == 1 ? Wk : seg == 2 ? Wv : Wf;
  short* d = seg == 0 ? cwq : seg == 1 ? cwk : seg == 2 ? cwv : cwf;
  const size_t base = (size_t)(bx & 63) * 16384;
#pragma unroll
  for (int it = 0; it < 4; it++) {
    const size_t i = base + (size_t)it * 4096 + (size_t)t * 16;
    const fx4 a0 = *(const fx4*)(s + i);
    const fx4 a1 = *(const fx4*)(s + i + 4);
    const fx4 a2 = *(const fx4*)(s + i + 8);
    const fx4 a3 = *(const fx4*)(s + i + 12);
    sx8 o0, o1;
    o0[0] = (short)f2bf(a0[0]); o0[1] = (short)f2bf(a0[1]);
    o0[2] = (short)f2bf(a0[2]); o0[3] = (short)f2bf(a0[3]);
    o0[4] = (short)f2bf(a1[0]); o0[5] = (short)f2bf(a1[1]);
    o0[6] = (short)f2bf(a1[2]); o0[7] = (short)f2bf(a1[3]);
    o1[0] = (short)f2bf(a2[0]); o1[1] = (short)f2bf(a2[1]);
    o1[2] = (short)f2bf(a2[2]); o1[3] = (short)f2bf(a2[3]);
    o1[4] = (short)f2bf(a3[0]); o1[5] = (short)f2bf(a3[1]);
    o1[6] = (short)f2bf(a3[2]); o1[7] = (short)f2bf(a3[3]);
    *(sx8*)(d + i) = o0;
    *(sx8*)(d + i + 8) = o1;
  }
}

// ---------------- GEMM body: C = alpha*(A[M,K] @ B[N,K]^T + bias) ------------
// MODE 0: bf16 row-major C.  MODE 1: f32 row-major C.
// MODE 2: bf16 V^T output Vt[b][d][kl] with 8B-half swap when (d&8).
// MT: 128 (4 waves 2x2, acc 4x4) or 64 (4 waves 1x4, acc 4x2).
// AF32: A is f32. T14 schedule — A(k+1) loads issued AFTER the staging
//   barrier (in flight across the whole compute phase), consumed next iter as
//   cvt_pk + ds_write into the same swizzled slots glds16 would fill. Keeps
//   staging async; fragment-read path identical to the bf16 path.
// BK=64, XOR-swizzled LDS, MFMA 16x16x32.
// M>=8192: XCD swizzle — all 8 n-tiles of an A m-strip share bx%8 (one XCD).
template <int MODE, int MT, int AF32>
__device__ __forceinline__ void gemm_body(short* sA, short* sB,
                                          const void* __restrict__ Aptr,
                                          const short* __restrict__ Bw,
                                          const float* __restrict__ bias,
                                          void* __restrict__ Cptr, int M, int N,
                                          int K, float alpha, int bx) {
  const int t = threadIdx.x;
  const int lane = t & 63;
  const int w = t >> 6;
  const int quad = lane >> 4;
  const int l16 = lane & 15;
  const int x7 = l16 & 7;
  int m0, n0;
  if (M >= 8192) {
    const int ml = bx & 7, nn = (bx >> 3) & 7, mh = bx >> 6;
    m0 = (mh * 8 + ml) * MT;
    n0 = nn << 7;
  } else {
    const int ntile = N >> 7;
    n0 = (bx % ntile) << 7;
    m0 = (bx / ntile) * MT;
  }
  constexpr int NI = (MT == 128) ? 4 : 2;
  constexpr int NJ = (MT == 128) ? 4 : 2;
  const int wm = (MT == 128) ? ((w >> 1) << 6) : 0;
  const int wn = (MT == 128) ? ((w & 1) << 6) : (w << 5);
  const fx4 fzero = {0.f, 0.f, 0.f, 0.f};
  fx4 acc[4][NI];
#pragma unroll
  for (int i = 0; i < 4; i++)
#pragma unroll
    for (int j = 0; j < NI; j++) acc[i][j] = fzero;

  const int srow = lane >> 3;
  const int scb = lane & 7;
  const float* Af = (const float*)Aptr;
  const short* Ab = (const short*)Aptr;
  fx4 ra[NJ][2];

  if (AF32) {  // prologue: A(0) loads
#pragma unroll
    for (int j = 0; j < NJ; j++) {
      const int rbase = (MT == 128) ? (w * 32 + j * 8) : (j * 32 + w * 8);
      const int row = rbase + srow;
      const int cb = scb ^ (row & 7);
      const float* src = Af + (size_t)(m0 + row) * K + cb * 8;
      ra[j][0] = *(const fx4*)src;
      ra[j][1] = *(const fx4*)(src + 4);
    }
  }

  for (int k0 = 0; k0 < K; k0 += 64) {
    __syncthreads();  // compute of previous tile done; LDS free
    if (AF32) {
      // cvt + write A(k): loads have been in flight for a full compute phase
#pragma unroll
      for (int j = 0; j < NJ; j++) {
        const int rbase = (MT == 128) ? (w * 32 + j * 8) : (j * 32 + w * 8);
        sx8 o;
        unsigned* ou = (unsigned*)&o;
        ou[0] = cvtpk(ra[j][0][0], ra[j][0][1]);
        ou[1] = cvtpk(ra[j][0][2], ra[j][0][3]);
        ou[2] = cvtpk(ra[j][1][0], ra[j][1][1]);
        ou[3] = cvtpk(ra[j][1][2], ra[j][1][3]);
        *(sx8*)(&sA[rbase * 64 + lane * 8]) = o;
      }
    } else {
#pragma unroll
      for (int j = 0; j < NJ; j++) {
        const int rbase = (MT == 128) ? (w * 32 + j * 8) : (j * 32 + w * 8);
        const int row = rbase + srow;
        const int cb = scb ^ (row & 7);
        glds16(Ab + (size_t)(m0 + row) * K + k0 + cb * 8, &sA[rbase * 64]);
      }
    }
#pragma unroll
    for (int j = 0; j < 4; j++) {
      const int row = w * 32 + j * 8 + srow;
      const int cb = scb ^ (row & 7);
      glds16(Bw + (size_t)(n0 + row) * K + k0 + cb * 8, &sB[(w * 32 + j * 8) * 64]);
    }
    __syncthreads();  // staging visible (drains B-glds only)
    if (AF32 && k0 + 64 < K) {
      // issue A(k+1) NOW: rides under the whole MFMA phase below
#pragma unroll
      for (int j = 0; j < NJ; j++) {
        const int rbase = (MT == 128) ? (w * 32 + j * 8) : (j * 32 + w * 8);
        const int row = rbase + srow;
        const int cb = scb ^ (row & 7);
        const float* src = Af + (size_t)(m0 + row) * K + (k0 + 64) + cb * 8;
        ra[j][0] = *(const fx4*)src;
        ra[j][1] = *(const fx4*)(src + 4);
      }
    }
#pragma unroll
    for (int kc = 0; kc < 2; kc++) {
      const int cbp = ((kc * 4 + quad) ^ x7) * 8;
      sx8 fa[4], fb[NI];
#pragma unroll
      for (int i = 0; i < 4; i++)
        fa[i] = *(const sx8*)(&sA[(wm + i * 16 + l16) * 64 + cbp]);
#pragma unroll
      for (int i = 0; i < NI; i++)
        fb[i] = *(const sx8*)(&sB[(wn + i * 16 + l16) * 64 + cbp]);
#pragma unroll
      for (int mi = 0; mi < 4; mi++)
#pragma unroll
        for (int ni = 0; ni < NI; ni++)
          acc[mi][ni] = MFMA32(fa[mi], fb[ni], acc[mi][ni]);
    }
  }
  // epilogue: C/D layout col=lane&15, row=quad*4+reg
#pragma unroll
  for (int ni = 0; ni < NI; ni++) {
    const int col = n0 + wn + ni * 16 + l16;
    const float bval = bias[col];
    if (MODE == 2) {
#pragma unroll
      for (int mi = 0; mi < 4; mi++) {
        const int rowb = m0 + wm + mi * 16 + quad * 4;
        const int bb = rowb >> 13;
        const int kl = (rowb & 8191) ^ ((col & 8) ? 4 : 0);
        sx4 pkv;
#pragma unroll
        for (int r = 0; r < 4; r++) pkv[r] = (short)f2bf(acc[mi][ni][r] + bval);
        *(sx4*)((unsigned short*)Cptr + ((size_t)bb * 1024 + col) * 8192 + kl) = pkv;
      }
    } else {
#pragma unroll
      for (int mi = 0; mi < 4; mi++)
#pragma unroll
        for (int r = 0; r < 4; r++) {
          const int row = m0 + wm + mi * 16 + quad * 4 + r;
          const float v = (acc[mi][ni][r] + bval) * alpha;
          if (MODE == 1) ((float*)Cptr)[(size_t)row * N + col] = v;
          else ((unsigned short*)Cptr)[(size_t)row * N + col] = f2bf(v);
        }
    }
  }
}

// K-projection (A = f32 ink): grid 1024
__global__ __launch_bounds__(256) void k_gemm_k(const float* __restrict__ ink,
                                                const short* __restrict__ cwk,
                                                const float* __restrict__ bk,
                                                short* __restrict__ Kp) {
  __shared__ __align__(16) short smem[16384];
  gemm_body<0, 128, 1>(smem, smem + 8192, ink, cwk, bk, Kp, 16384, 1024, 1024,
                       1.f, blockIdx.x);
}

// V-projection (fused transpose, A = f32 inv) + Q-projection (A = f32 inq)
__global__ __launch_bounds__(256) void k_proj_vq(
    const float* __restrict__ inv, const short* __restrict__ cwv,
    const float* __restrict__ bv, short* __restrict__ Vt,
    const float* __restrict__ inq, const short* __restrict__ cwq,
    const float* __restrict__ bq, short* __restrict__ Qp, float alpha_q) {
  __shared__ __align__(16) short smem[16384];
  const int bx = blockIdx.x;
  if (bx < 128)
    gemm_body<0, 64, 1>(smem, smem + 8192, inq, cwq, bq, Qp, 1024, 1024, 1024,
                        alpha_q, bx);
  else
    gemm_body<2, 128, 1>(smem, smem + 8192, inv, cwv, bv, Vt, 16384, 1024, 1024,
                         1.f, bx - 128);
}

// out-projection (A = bf16 summed): grid 128
__global__ __launch_bounds__(256) void k_gemm_out(const short* __restrict__ summed,
                                                  const short* __restrict__ cwf,
                                                  const float* __restrict__ bf,
                                                  float* __restrict__ out) {
  __shared__ __align__(16) short smem[16384];
  gemm_body<1, 64, 0>(smem, smem + 8192, summed, cwf, bf, out, 1024, 1024, 1024,
                      1.f, blockIdx.x);
}

// ---------------- flash attention (S^T trick, no-max softmax) ----------------
// grid 1024, XCD-swizzled: x = (g&7) + 8*(qt + 8*(g>>3)), g=(b*8+h)*8+s.
__global__ __launch_bounds__(256, 4) void k_attn(const short* __restrict__ Qp,
                                                 const short* __restrict__ Kp,
                                                 const short* __restrict__ Vt,
                                                 const u64* __restrict__ mb,
                                                 float* __restrict__ ml,
                                                 float* __restrict__ Op) {
  __shared__ __align__(16) short sK[8192];  // 64 keys x 128 d (256B rows, swizzled)
  __shared__ __align__(16) short sV[8192];  // 128 d x 64 keys (128B rows, swizzled)
  const int x = blockIdx.x;
  const int gl = x & 7;
  const int qt = (x >> 3) & 7;
  const int gh = x >> 6;
  const int g = gh * 8 + gl;  // 0..127
  const int s = g & 7;
  const int h = (g >> 3) & 7;
  const int b = g >> 6;
  const int li = ((b * 8 + h) * 8 + qt) * 8 + s;  // logical index for ml/Op
  const int t = threadIdx.x;
  const int lane = t & 63;
  const int w = t >> 6;
  const int quad = lane >> 4;
  const int l16 = lane & 15;
  const int x7 = l16 & 7;
  const int q0 = qt << 6;
  const fx4 fzero = {0.f, 0.f, 0.f, 0.f};

  const short* qbase = Qp + (size_t)(b * 512 + q0 + w * 16 + l16) * 1024 + h * 128;
  sx8 aq[4];
#pragma unroll
  for (int kc = 0; kc < 4; kc++) aq[kc] = *(const sx8*)(qbase + kc * 32 + quad * 8);

  fx4 Ot[8];
#pragma unroll
  for (int d = 0; d < 8; d++) Ot[d] = fzero;
  float lsum = 0.f;

  const short* kbase = Kp + (size_t)(b * 8192 + s * 1024) * 1024 + h * 128;
  const short* vbase = Vt + (size_t)(b * 1024 + h * 128) * 8192 + s * 1024;
  const u64* wdp = mb + (size_t)(b * 512 + q0 + w * 16 + l16) * 128 + s * 16;
  const int srow4 = lane >> 4, scb16 = lane & 15;
  const int srow8 = lane >> 3, scb8 = lane & 7;
  const int h4 = ((quad & 1) ^ ((l16 >> 3) & 1)) * 4;  // 8B-half parity (bank spread)

  for (int kt = 0; kt < 16; kt++) {
    __syncthreads();
#pragma unroll
    for (int j = 0; j < 4; j++) {  // K tile: 4 rows/issue
      const int row = (w * 4 + j) * 4 + srow4;
      const int cb = scb16 ^ (row & 7);
      glds16(kbase + (size_t)(kt * 64 + row) * 1024 + cb * 8, &sK[(w * 4 + j) * 512]);
    }
#pragma unroll
    for (int j = 0; j < 4; j++) {  // V^T tile: 8 rows/issue
      const int row = (w * 4 + j) * 8 + srow8;
      const int cb = scb8 ^ (row & 7);
      glds16(vbase + (size_t)row * 8192 + kt * 64 + cb * 8, &sV[(w * 4 + j) * 512]);
    }
    const u64 wd = wdp[kt];
    __syncthreads();
    const unsigned lo = (unsigned)wd, hi = (unsigned)(wd >> 32);
    sx4 pk[4];
#pragma unroll
    for (int nt = 0; nt < 4; nt++) {
      fx4 a = fzero;
#pragma unroll
      for (int kc = 0; kc < 4; kc++) {
        const sx8 kf = *(const sx8*)(&sK[(nt * 16 + l16) * 128 + ((kc * 4 + quad) ^ x7) * 8]);
        a = MFMA32(kf, aq[kc], a);  // S^T: row=key, col=q
      }
      const unsigned bits = (nt & 2) ? hi : lo;
      const int sh = (nt & 1) * 16 + quad * 4;
      float pv[4];
#pragma unroll
      for (int r = 0; r < 4; r++) {
        const float e = __builtin_amdgcn_exp2f(a[r]);  // scale*log2e folded into Qp
        pv[r] = ((bits >> (sh + r)) & 1u) ? e : 0.f;
        lsum += pv[r];
      }
      sx4 pko;
      ((unsigned*)&pko)[0] = __builtin_amdgcn_perm(
          __float_as_uint(pv[1]) + 0x8000u, __float_as_uint(pv[0]) + 0x8000u, 0x07060302u);
      ((unsigned*)&pko)[1] = __builtin_amdgcn_perm(
          __float_as_uint(pv[3]) + 0x8000u, __float_as_uint(pv[2]) + 0x8000u, 0x07060302u);
      pk[nt] = pko;
    }
#pragma unroll
    for (int dt = 0; dt < 8; dt++) {
      fx4 o = Ot[dt];
#pragma unroll
      for (int nt = 0; nt < 4; nt++) {
        const int cb = (2 * nt + (quad >> 1)) ^ x7;
        const sx4 vf = *(const sx4*)(&sV[(dt * 16 + l16) * 64 + cb * 8 + h4]);
        o = MFMA16(vf, pk[nt], o);  // O^T: row=d, col=q
      }
      Ot[dt] = o;
    }
  }
  lsum += __shfl_xor(lsum, 16, 64);
  lsum += __shfl_xor(lsum, 32, 64);
  if (lane < 16) ml[(size_t)li * 64 + w * 16 + l16] = lsum;
  float* ob = Op + (size_t)li * 8192 + (w * 16 + l16) * 128 + quad * 4;
#pragma unroll
  for (int dt = 0; dt < 8; dt++) *(fx4*)(ob + dt * 16) = Ot[dt];
}

// ---------------- combine 8 KL-split partials -> summed bf16 -----------------
// grid 256: each block does one (b,h,qt) x one 64-wide d-half (full CU coverage)
__global__ __launch_bounds__(256) void k_combine(const float* __restrict__ ml,
                                                 const float* __restrict__ Op,
                                                 short* __restrict__ summed) {
  const int bx = blockIdx.x;
  const int xc = bx >> 1;        // qt + 8*h + 64*b
  const int dh = (bx & 1) * 64;  // d-half
  const int qt = xc & 7;
  const int h = (xc >> 3) & 7;
  const int b = xc >> 6;
  const int t = threadIdx.x;
  const int row = t >> 2;
  const int dg = dh + (t & 3) * 16;
  float L = 0.f;
#pragma unroll
  for (int s = 0; s < 8; s++) L += ml[(size_t)(xc * 8 + s) * 64 + row];
  float o[16];
#pragma unroll
  for (int i = 0; i < 16; i++) o[i] = 0.f;
  if (L != 0.f) {
#pragma unroll
    for (int s = 0; s < 8; s++) {
      const float* src = Op + (size_t)(xc * 8 + s) * 8192 + row * 128 + dg;
#pragma unroll
      for (int i = 0; i < 4; i++) {
        const fx4 v = *(const fx4*)(src + i * 4);
        o[i * 4 + 0] += v[0]; o[i * 4 + 1] += v[1];
        o[i * 4 + 2] += v[2]; o[i * 4 + 3] += v[3];
      }
    }
    const float inv = 1.f / L;
#pragma unroll
    for (int i = 0; i < 16; i++) o[i] *= inv;
  }
  short* dst = summed + (size_t)(b * 512 + qt * 64 + row) * 1024 + h * 128 + dg;
#pragma unroll
  for (int i = 0; i < 2; i++) {
    sx8 pkv;
#pragma unroll
    for (int j = 0; j < 8; j++) pkv[j] = (short)f2bf(o[i * 8 + j]);
    *(sx8*)(dst + i * 8) = pkv;
  }
}

// ---------------- host ------------------------------------------------------
extern "C" void kernel_launch(void* const* d_in, const int* in_sizes, int n_in,
                              void* d_out, int out_size, void* d_ws, size_t ws_size,
                              hipStream_t stream) {
  (void)in_sizes; (void)n_in; (void)out_size; (void)ws_size;
  const float* inq = (const float*)d_in[0];
  const float* ink = (const float*)d_in[1];
  const float* inv = (const float*)d_in[2];
  const int* mask = (const int*)d_in[3];
  const float* Wq = (const float*)d_in[4];
  const float* bq = (const float*)d_in[5];
  const float* Wk = (const float*)d_in[6];
  const float* bk = (const float*)d_in[7];
  const float* Wv = (const float*)d_in[8];
  const float* bv = (const float*)d_in[9];
  const float* Wf = (const float*)d_in[10];
  const float* bf = (const float*)d_in[11];

  char* ws = (char*)d_ws;
  short* Vt = (short*)(ws + 0);            // 33.5MB bf16
  short* Kp = (short*)(ws + 33554432);     // 33.5MB bf16
  float* Op = (float*)(ws + 67108864);     // 33.5MB f32 attn partials
  short* cwq = (short*)(ws + 102760448);   // 2MB each
  short* cwk = (short*)(ws + 104857600);
  short* cwv = (short*)(ws + 106954752);
  short* cwf = (short*)(ws + 109051904);
  short* Qp = (short*)(ws + 111149056);
  short* summed = (short*)(ws + 113246208);
  u64* mb = (u64*)(ws + 115343360);
  float* ml = (float*)(ws + 116391936);

  const float alpha_q = 0.12751757f;  // (1/sqrt(128)) * log2(e)

  k_prep<<<2304, 256, 0, stream>>>(Wq, Wk, Wv, Wf, mask, cwq, cwk, cwv, cwf, mb);
  k_gemm_k<<<1024, 256, 0, stream>>>(ink, cwk, bk, Kp);
  k_proj_vq<<<1152, 256, 0, stream>>>(inv, cwv, bv, Vt, inq, cwq, bq, Qp, alpha_q);
  k_attn<<<1024, 256, 0, stream>>>(Qp, Kp, Vt, mb, ml, Op);
  k_combine<<<256, 256, 0, stream>>>(ml, Op, summed);
  k_gemm_out<<<128, 256, 0, stream>>>(summed, cwf, bf, (float*)d_out);
}

// Round 4
// 380.805 us; speedup vs baseline: 1.0642x; 1.0165x over previous
//
#include <hip/hip_runtime.h>
#include <hip/hip_bf16.h>
#include <math.h>

// B=2 QL=512 KL=8192 D=1024 H=8 HD=128
typedef __attribute__((ext_vector_type(4))) float fx4;
typedef __attribute__((ext_vector_type(4))) short sx4;
typedef __attribute__((ext_vector_type(8))) short sx8;
typedef unsigned long long u64;

#define MFMA16(a, b, c) __builtin_amdgcn_mfma_f32_16x16x16bf16_1k(a, b, c, 0, 0, 0)
#define MFMA32(a, b, c) __builtin_amdgcn_mfma_f32_16x16x32_bf16(a, b, c, 0, 0, 0)

__device__ __forceinline__ unsigned short f2bf(float f) {
  unsigned int u = __float_as_uint(f);
  return (unsigned short)((u + 0x7fffu + ((u >> 16) & 1u)) >> 16);  // RNE
}

// packed f32x2 -> bf16x2 (RNE)
__device__ __forceinline__ unsigned cvtpk(float lo, float hi) {
  unsigned r;
  asm("v_cvt_pk_bf16_f32 %0, %1, %2" : "=v"(r) : "v"(lo), "v"(hi));
  return r;
}

// async global->LDS, 16B per lane; LDS dest is wave-uniform base + lane*16
typedef const __attribute__((address_space(1))) char* gc1p;
typedef __attribute__((address_space(3))) char* lc3p;
__device__ __forceinline__ void glds16(const void* g, const void* lds_uniform) {
  gc1p gp = (gc1p)(unsigned long long)(uintptr_t)g;
  lc3p lp = (lc3p)(unsigned)__builtin_amdgcn_readfirstlane((int)(unsigned)(uintptr_t)lds_uniform);
  __builtin_amdgcn_global_load_lds(gp, lp, 16, 0, 0);
}

// ---------------- prep (slim): weights f32->bf16 + mask pack ----------------
// [0,256): Wq,Wk,Wv,Wf (64 blocks each, 16384 elems/block)
// [256,2304): mask pack, 4 rows/block
__global__ __launch_bounds__(256) void k_prep(
    const float* __restrict__ Wq, const float* __restrict__ Wk,
    const float* __restrict__ Wv, const float* __restrict__ Wf,
    const int* __restrict__ mask, short* cwq, short* cwk, short* cwv,
    short* cwf, u64* __restrict__ mb) {
  __shared__ unsigned char nib[4][256];
  const int bx = blockIdx.x;
  const int t = threadIdx.x;
  if (bx >= 256) {  // mask pack: 4 rows/block, 4 independent 16B loads/lane
    const int mrow0 = (bx - 256) * 4;
#pragma unroll
    for (int j = 0; j < 4; j++) {
      const int4 m = *(const int4*)(mask + (size_t)(mrow0 + j) * 1024 + t * 4);
      nib[j][t] = (unsigned char)((m.x != 0) | ((m.y != 0) << 1) |
                                  ((m.z != 0) << 2) | ((m.w != 0) << 3));
    }
    __syncthreads();
    if (t < 64) {
      const int j = t >> 4, i = t & 15;
      u64 wv = 0;
#pragma unroll
      for (int k = 0; k < 16; k++)
        wv |= (u64)(nib[j][i * 16 + k] & 0xF) << (4 * k);
      mb[(size_t)(mrow0 + j) * 16 + i] = wv;
    }
    return;
  }
  const int seg = bx >> 6;
  const float* s = seg == 0 ? Wq : seg == 1 ? Wk : seg == 2 ? Wv : Wf;
  short* d = seg == 0 ? cwq : seg == 1 ? cwk : seg == 2 ? cwv : cwf;
  const size_t base = (size_t)(bx & 63) * 16384;
#pragma unroll
  for (int it = 0; it < 4; it++) {
    const size_t i = base + (size_t)it * 4096 + (size_t)t * 16;
    const fx4 a0 = *(const fx4*)(s + i);
    const fx4 a1 = *(const fx4*)(s + i + 4);
    const fx4 a2 = *(const fx4*)(s + i + 8);
    const fx4 a3 = *(const fx4*)(s + i + 12);
    sx8 o0, o1;
    o0[0] = (short)f2bf(a0[0]); o0[1] = (short)f2bf(a0[1]);
    o0[2] = (short)f2bf(a0[2]); o0[3] = (short)f2bf(a0[3]);
    o0[4] = (short)f2bf(a1[0]); o0[5] = (short)f2bf(a1[1]);
    o0[6] = (short)f2bf(a1[2]); o0[7] = (short)f2bf(a1[3]);
    o1[0] = (short)f2bf(a2[0]); o1[1] = (short)f2bf(a2[1]);
    o1[2] = (short)f2bf(a2[2]); o1[3] = (short)f2bf(a2[3]);
    o1[4] = (short)f2bf(a3[0]); o1[5] = (short)f2bf(a3[1]);
    o1[6] = (short)f2bf(a3[2]); o1[7] = (short)f2bf(a3[3]);
    *(sx8*)(d + i) = o0;
    *(sx8*)(d + i + 8) = o1;
  }
}

// ---------------- GEMM body: C = alpha*(A[M,K] @ B[N,K]^T + bias) ------------
// MODE 0: bf16 row-major C.  MODE 1: f32 row-major C.
// MODE 2: bf16 V^T output Vt[b][d][kl] with 8B-half swap when (d&8).
// MT: 128 (4 waves 2x2, acc 4x4) or 64 (4 waves 1x4, acc 4x2).
// AF32: A is f32 (reg-stage: load f32x8 -> cvt_pk -> ds_write); else bf16 glds.
// T3-minimum schedule: double-buffered sA/sB (buf stride 8192 shorts), next
// tile's staging ISSUED BEFORE current tile's MFMA, ONE barrier per K-step at
// the end. The compiler's vmcnt(0)-before-barrier then drains loads that have
// had a full compute phase in flight.
// BK=64, XOR-swizzled LDS, MFMA 16x16x32.
// M>=8192: XCD swizzle — all 8 n-tiles of an A m-strip share bx%8 (one XCD).
template <int MODE, int MT, int AF32>
__device__ __forceinline__ void gemm_body(short* sA, short* sB,
                                          const void* __restrict__ Aptr,
                                          const short* __restrict__ Bw,
                                          const float* __restrict__ bias,
                                          void* __restrict__ Cptr, int M, int N,
                                          int K, float alpha, int bx) {
  const int t = threadIdx.x;
  const int lane = t & 63;
  const int w = t >> 6;
  const int quad = lane >> 4;
  const int l16 = lane & 15;
  const int x7 = l16 & 7;
  int m0, n0;
  if (M >= 8192) {
    const int ml = bx & 7, nn = (bx >> 3) & 7, mh = bx >> 6;
    m0 = (mh * 8 + ml) * MT;
    n0 = nn << 7;
  } else {
    const int ntile = N >> 7;
    n0 = (bx % ntile) << 7;
    m0 = (bx / ntile) * MT;
  }
  constexpr int NI = (MT == 128) ? 4 : 2;
  constexpr int NJ = (MT == 128) ? 4 : 2;
  const int wm = (MT == 128) ? ((w >> 1) << 6) : 0;
  const int wn = (MT == 128) ? ((w & 1) << 6) : (w << 5);
  const fx4 fzero = {0.f, 0.f, 0.f, 0.f};
  fx4 acc[4][NI];
#pragma unroll
  for (int i = 0; i < 4; i++)
#pragma unroll
    for (int j = 0; j < NI; j++) acc[i][j] = fzero;

  const int srow = lane >> 3;
  const int scb = lane & 7;
  const float* Af = (const float*)Aptr;
  const short* Ab = (const short*)Aptr;
  fx4 ra[NJ][2];

  // ---- prologue: stage tile 0 into buf 0 ----
  if (AF32) {
#pragma unroll
    for (int j = 0; j < NJ; j++) {
      const int rbase = (MT == 128) ? (w * 32 + j * 8) : (j * 32 + w * 8);
      const int row = rbase + srow;
      const int cb = scb ^ (row & 7);
      const float* src = Af + (size_t)(m0 + row) * K + cb * 8;
      ra[j][0] = *(const fx4*)src;
      ra[j][1] = *(const fx4*)(src + 4);
    }
  } else {
#pragma unroll
    for (int j = 0; j < NJ; j++) {
      const int rbase = (MT == 128) ? (w * 32 + j * 8) : (j * 32 + w * 8);
      const int row = rbase + srow;
      const int cb = scb ^ (row & 7);
      glds16(Ab + (size_t)(m0 + row) * K + cb * 8, &sA[rbase * 64]);
    }
  }
#pragma unroll
  for (int j = 0; j < 4; j++) {
    const int row = w * 32 + j * 8 + srow;
    const int cb = scb ^ (row & 7);
    glds16(Bw + (size_t)(n0 + row) * K + cb * 8, &sB[(w * 32 + j * 8) * 64]);
  }
  if (AF32) {
#pragma unroll
    for (int j = 0; j < NJ; j++) {
      const int rbase = (MT == 128) ? (w * 32 + j * 8) : (j * 32 + w * 8);
      sx8 o;
      unsigned* ou = (unsigned*)&o;
      ou[0] = cvtpk(ra[j][0][0], ra[j][0][1]);
      ou[1] = cvtpk(ra[j][0][2], ra[j][0][3]);
      ou[2] = cvtpk(ra[j][1][0], ra[j][1][1]);
      ou[3] = cvtpk(ra[j][1][2], ra[j][1][3]);
      *(sx8*)(&sA[rbase * 64 + lane * 8]) = o;
    }
  }
  __syncthreads();

  int buf = 0;
  for (int k0 = 0; k0 < K; k0 += 64) {
    const int nb = buf ^ 1;
    const bool more = (k0 + 64 < K);
    // ---- prefetch tile k+1 into buf^1 (in flight across the MFMA phase) ----
    if (more) {
#pragma unroll
      for (int j = 0; j < 4; j++) {
        const int row = w * 32 + j * 8 + srow;
        const int cb = scb ^ (row & 7);
        glds16(Bw + (size_t)(n0 + row) * K + (k0 + 64) + cb * 8,
               &sB[nb * 8192 + (w * 32 + j * 8) * 64]);
      }
      if (AF32) {
#pragma unroll
        for (int j = 0; j < NJ; j++) {
          const int rbase = (MT == 128) ? (w * 32 + j * 8) : (j * 32 + w * 8);
          const int row = rbase + srow;
          const int cb = scb ^ (row & 7);
          const float* src = Af + (size_t)(m0 + row) * K + (k0 + 64) + cb * 8;
          ra[j][0] = *(const fx4*)src;
          ra[j][1] = *(const fx4*)(src + 4);
        }
      } else {
#pragma unroll
        for (int j = 0; j < NJ; j++) {
          const int rbase = (MT == 128) ? (w * 32 + j * 8) : (j * 32 + w * 8);
          const int row = rbase + srow;
          const int cb = scb ^ (row & 7);
          glds16(Ab + (size_t)(m0 + row) * K + (k0 + 64) + cb * 8,
                 &sA[nb * 8192 + rbase * 64]);
        }
      }
    }
    // ---- compute tile k from buf ----
    const short* pA = sA + buf * 8192;
    const short* pB = sB + buf * 8192;
#pragma unroll
    for (int kc = 0; kc < 2; kc++) {
      const int cbp = ((kc * 4 + quad) ^ x7) * 8;
      sx8 fa[4], fb[NI];
#pragma unroll
      for (int i = 0; i < 4; i++)
        fa[i] = *(const sx8*)(&pA[(wm + i * 16 + l16) * 64 + cbp]);
#pragma unroll
      for (int i = 0; i < NI; i++)
        fb[i] = *(const sx8*)(&pB[(wn + i * 16 + l16) * 64 + cbp]);
#pragma unroll
      for (int mi = 0; mi < 4; mi++)
#pragma unroll
        for (int ni = 0; ni < NI; ni++)
          acc[mi][ni] = MFMA32(fa[mi], fb[ni], acc[mi][ni]);
    }
    // ---- A(k+1) cvt + ds_write into buf^1 (loads have had the MFMA phase) --
    if (AF32 && more) {
#pragma unroll
      for (int j = 0; j < NJ; j++) {
        const int rbase = (MT == 128) ? (w * 32 + j * 8) : (j * 32 + w * 8);
        sx8 o;
        unsigned* ou = (unsigned*)&o;
        ou[0] = cvtpk(ra[j][0][0], ra[j][0][1]);
        ou[1] = cvtpk(ra[j][0][2], ra[j][0][3]);
        ou[2] = cvtpk(ra[j][1][0], ra[j][1][1]);
        ou[3] = cvtpk(ra[j][1][2], ra[j][1][3]);
        *(sx8*)(&sA[nb * 8192 + rbase * 64 + lane * 8]) = o;
      }
    }
    __syncthreads();  // single barrier per K-step: drains staged loads/writes
    buf = nb;
  }
  // epilogue: C/D layout col=lane&15, row=quad*4+reg
#pragma unroll
  for (int ni = 0; ni < NI; ni++) {
    const int col = n0 + wn + ni * 16 + l16;
    const float bval = bias[col];
    if (MODE == 2) {
#pragma unroll
      for (int mi = 0; mi < 4; mi++) {
        const int rowb = m0 + wm + mi * 16 + quad * 4;
        const int bb = rowb >> 13;
        const int kl = (rowb & 8191) ^ ((col & 8) ? 4 : 0);
        sx4 pkv;
#pragma unroll
        for (int r = 0; r < 4; r++) pkv[r] = (short)f2bf(acc[mi][ni][r] + bval);
        *(sx4*)((unsigned short*)Cptr + ((size_t)bb * 1024 + col) * 8192 + kl) = pkv;
      }
    } else {
#pragma unroll
      for (int mi = 0; mi < 4; mi++)
#pragma unroll
        for (int r = 0; r < 4; r++) {
          const int row = m0 + wm + mi * 16 + quad * 4 + r;
          const float v = (acc[mi][ni][r] + bval) * alpha;
          if (MODE == 1) ((float*)Cptr)[(size_t)row * N + col] = v;
          else ((unsigned short*)Cptr)[(size_t)row * N + col] = f2bf(v);
        }
    }
  }
}

// ---------------- merged projections: K + V(fused transpose) + Q ------------
// grid 2176: [0,1024) K-proj, [1024,2048) V-proj, [2048,2176) Q-proj
__global__ __launch_bounds__(256) void k_proj(
    const float* __restrict__ ink, const short* __restrict__ cwk,
    const float* __restrict__ bk, short* __restrict__ Kp,
    const float* __restrict__ inv, const short* __restrict__ cwv,
    const float* __restrict__ bv, short* __restrict__ Vt,
    const float* __restrict__ inq, const short* __restrict__ cwq,
    const float* __restrict__ bq, short* __restrict__ Qp, float alpha_q) {
  __shared__ __align__(16) short smem[32768];  // 64 KB: sA dbuf + sB dbuf
  const int bx = blockIdx.x;
  if (bx < 1024)
    gemm_body<0, 128, 1>(smem, smem + 16384, ink, cwk, bk, Kp, 16384, 1024,
                         1024, 1.f, bx);
  else if (bx < 2048)
    gemm_body<2, 128, 1>(smem, smem + 16384, inv, cwv, bv, Vt, 16384, 1024,
                         1024, 1.f, bx - 1024);
  else
    gemm_body<0, 64, 1>(smem, smem + 16384, inq, cwq, bq, Qp, 1024, 1024, 1024,
                        alpha_q, bx - 2048);
}

// out-projection (A = bf16 summed): grid 128
__global__ __launch_bounds__(256) void k_gemm_out(const short* __restrict__ summed,
                                                  const short* __restrict__ cwf,
                                                  const float* __restrict__ bf,
                                                  float* __restrict__ out) {
  __shared__ __align__(16) short smem[32768];
  gemm_body<1, 64, 0>(smem, smem + 16384, summed, cwf, bf, out, 1024, 1024,
                      1024, 1.f, blockIdx.x);
}

// ---------------- flash attention (S^T trick, no-max softmax) ----------------
// grid 1024, XCD-swizzled: x = (g&7) + 8*(qt + 8*(g>>3)), g=(b*8+h)*8+s.
__global__ __launch_bounds__(256, 4) void k_attn(const short* __restrict__ Qp,
                                                 const short* __restrict__ Kp,
                                                 const short* __restrict__ Vt,
                                                 const u64* __restrict__ mb,
                                                 float* __restrict__ ml,
                                                 float* __restrict__ Op) {
  __shared__ __align__(16) short sK[8192];  // 64 keys x 128 d (256B rows, swizzled)
  __shared__ __align__(16) short sV[8192];  // 128 d x 64 keys (128B rows, swizzled)
  const int x = blockIdx.x;
  const int gl = x & 7;
  const int qt = (x >> 3) & 7;
  const int gh = x >> 6;
  const int g = gh * 8 + gl;  // 0..127
  const int s = g & 7;
  const int h = (g >> 3) & 7;
  const int b = g >> 6;
  const int li = ((b * 8 + h) * 8 + qt) * 8 + s;  // logical index for ml/Op
  const int t = threadIdx.x;
  const int lane = t & 63;
  const int w = t >> 6;
  const int quad = lane >> 4;
  const int l16 = lane & 15;
  const int x7 = l16 & 7;
  const int q0 = qt << 6;
  const fx4 fzero = {0.f, 0.f, 0.f, 0.f};

  const short* qbase = Qp + (size_t)(b * 512 + q0 + w * 16 + l16) * 1024 + h * 128;
  sx8 aq[4];
#pragma unroll
  for (int kc = 0; kc < 4; kc++) aq[kc] = *(const sx8*)(qbase + kc * 32 + quad * 8);

  fx4 Ot[8];
#pragma unroll
  for (int d = 0; d < 8; d++) Ot[d] = fzero;
  float lsum = 0.f;

  const short* kbase = Kp + (size_t)(b * 8192 + s * 1024) * 1024 + h * 128;
  const short* vbase = Vt + (size_t)(b * 1024 + h * 128) * 8192 + s * 1024;
  const u64* wdp = mb + (size_t)(b * 512 + q0 + w * 16 + l16) * 128 + s * 16;
  const int srow4 = lane >> 4, scb16 = lane & 15;
  const int srow8 = lane >> 3, scb8 = lane & 7;
  const int h4 = ((quad & 1) ^ ((l16 >> 3) & 1)) * 4;  // 8B-half parity (bank spread)

  for (int kt = 0; kt < 16; kt++) {
    __syncthreads();
#pragma unroll
    for (int j = 0; j < 4; j++) {  // K tile: 4 rows/issue
      const int row = (w * 4 + j) * 4 + srow4;
      const int cb = scb16 ^ (row & 7);
      glds16(kbase + (size_t)(kt * 64 + row) * 1024 + cb * 8, &sK[(w * 4 + j) * 512]);
    }
#pragma unroll
    for (int j = 0; j < 4; j++) {  // V^T tile: 8 rows/issue
      const int row = (w * 4 + j) * 8 + srow8;
      const int cb = scb8 ^ (row & 7);
      glds16(vbase + (size_t)row * 8192 + kt * 64 + cb * 8, &sV[(w * 4 + j) * 512]);
    }
    const u64 wd = wdp[kt];
    __syncthreads();
    const unsigned lo = (unsigned)wd, hi = (unsigned)(wd >> 32);
    sx4 pk[4];
#pragma unroll
    for (int nt = 0; nt < 4; nt++) {
      fx4 a = fzero;
#pragma unroll
      for (int kc = 0; kc < 4; kc++) {
        const sx8 kf = *(const sx8*)(&sK[(nt * 16 + l16) * 128 + ((kc * 4 + quad) ^ x7) * 8]);
        a = MFMA32(kf, aq[kc], a);  // S^T: row=key, col=q
      }
      const unsigned bits = (nt & 2) ? hi : lo;
      const int sh = (nt & 1) * 16 + quad * 4;
      float pv[4];
#pragma unroll
      for (int r = 0; r < 4; r++) {
        const float e = __builtin_amdgcn_exp2f(a[r]);  // scale*log2e folded into Qp
        pv[r] = ((bits >> (sh + r)) & 1u) ? e : 0.f;
        lsum += pv[r];
      }
      sx4 pko;
      ((unsigned*)&pko)[0] = __builtin_amdgcn_perm(
          __float_as_uint(pv[1]) + 0x8000u, __float_as_uint(pv[0]) + 0x8000u, 0x07060302u);
      ((unsigned*)&pko)[1] = __builtin_amdgcn_perm(
          __float_as_uint(pv[3]) + 0x8000u, __float_as_uint(pv[2]) + 0x8000u, 0x07060302u);
      pk[nt] = pko;
    }
#pragma unroll
    for (int dt = 0; dt < 8; dt++) {
      fx4 o = Ot[dt];
#pragma unroll
      for (int nt = 0; nt < 4; nt++) {
        const int cb = (2 * nt + (quad >> 1)) ^ x7;
        const sx4 vf = *(const sx4*)(&sV[(dt * 16 + l16) * 64 + cb * 8 + h4]);
        o = MFMA16(vf, pk[nt], o);  // O^T: row=d, col=q
      }
      Ot[dt] = o;
    }
  }
  lsum += __shfl_xor(lsum, 16, 64);
  lsum += __shfl_xor(lsum, 32, 64);
  if (lane < 16) ml[(size_t)li * 64 + w * 16 + l16] = lsum;
  float* ob = Op + (size_t)li * 8192 + (w * 16 + l16) * 128 + quad * 4;
#pragma unroll
  for (int dt = 0; dt < 8; dt++) *(fx4*)(ob + dt * 16) = Ot[dt];
}

// ---------------- combine 8 KL-split partials -> summed bf16 -----------------
// grid 256: each block does one (b,h,qt) x one 64-wide d-half (full CU coverage)
__global__ __launch_bounds__(256) void k_combine(const float* __restrict__ ml,
                                                 const float* __restrict__ Op,
                                                 short* __restrict__ summed) {
  const int bx = blockIdx.x;
  const int xc = bx >> 1;        // qt + 8*h + 64*b
  const int dh = (bx & 1) * 64;  // d-half
  const int qt = xc & 7;
  const int h = (xc >> 3) & 7;
  const int b = xc >> 6;
  const int t = threadIdx.x;
  const int row = t >> 2;
  const int dg = dh + (t & 3) * 16;
  float L = 0.f;
#pragma unroll
  for (int s = 0; s < 8; s++) L += ml[(size_t)(xc * 8 + s) * 64 + row];
  float o[16];
#pragma unroll
  for (int i = 0; i < 16; i++) o[i] = 0.f;
  if (L != 0.f) {
#pragma unroll
    for (int s = 0; s < 8; s++) {
      const float* src = Op + (size_t)(xc * 8 + s) * 8192 + row * 128 + dg;
#pragma unroll
      for (int i = 0; i < 4; i++) {
        const fx4 v = *(const fx4*)(src + i * 4);
        o[i * 4 + 0] += v[0]; o[i * 4 + 1] += v[1];
        o[i * 4 + 2] += v[2]; o[i * 4 + 3] += v[3];
      }
    }
    const float inv = 1.f / L;
#pragma unroll
    for (int i = 0; i < 16; i++) o[i] *= inv;
  }
  short* dst = summed + (size_t)(b * 512 + qt * 64 + row) * 1024 + h * 128 + dg;
#pragma unroll
  for (int i = 0; i < 2; i++) {
    sx8 pkv;
#pragma unroll
    for (int j = 0; j < 8; j++) pkv[j] = (short)f2bf(o[i * 8 + j]);
    *(sx8*)(dst + i * 8) = pkv;
  }
}

// ---------------- host ------------------------------------------------------
extern "C" void kernel_launch(void* const* d_in, const int* in_sizes, int n_in,
                              void* d_out, int out_size, void* d_ws, size_t ws_size,
                              hipStream_t stream) {
  (void)in_sizes; (void)n_in; (void)out_size; (void)ws_size;
  const float* inq = (const float*)d_in[0];
  const float* ink = (const float*)d_in[1];
  const float* inv = (const float*)d_in[2];
  const int* mask = (const int*)d_in[3];
  const float* Wq = (const float*)d_in[4];
  const float* bq = (const float*)d_in[5];
  const float* Wk = (const float*)d_in[6];
  const float* bk = (const float*)d_in[7];
  const float* Wv = (const float*)d_in[8];
  const float* bv = (const float*)d_in[9];
  const float* Wf = (const float*)d_in[10];
  const float* bf = (const float*)d_in[11];

  char* ws = (char*)d_ws;
  short* Vt = (short*)(ws + 0);            // 33.5MB bf16
  short* Kp = (short*)(ws + 33554432);     // 33.5MB bf16
  float* Op = (float*)(ws + 67108864);     // 33.5MB f32 attn partials
  short* cwq = (short*)(ws + 102760448);   // 2MB each
  short* cwk = (short*)(ws + 104857600);
  short* cwv = (short*)(ws + 106954752);
  short* cwf = (short*)(ws + 109051904);
  short* Qp = (short*)(ws + 111149056);
  short* summed = (short*)(ws + 113246208);
  u64* mb = (u64*)(ws + 115343360);
  float* ml = (float*)(ws + 116391936);

  const float alpha_q = 0.12751757f;  // (1/sqrt(128)) * log2(e)

  k_prep<<<2304, 256, 0, stream>>>(Wq, Wk, Wv, Wf, mask, cwq, cwk, cwv, cwf, mb);
  k_proj<<<2176, 256, 0, stream>>>(ink, cwk, bk, Kp, inv, cwv, bv, Vt, inq, cwq,
                                   bq, Qp, alpha_q);
  k_attn<<<1024, 256, 0, stream>>>(Qp, Kp, Vt, mb, ml, Op);
  k_combine<<<256, 256, 0, stream>>>(ml, Op, summed);
  k_gemm_out<<<128, 256, 0, stream>>>(summed, cwf, bf, (float*)d_out);
}

// Round 5
// 351.487 us; speedup vs baseline: 1.1530x; 1.0834x over previous
//
#include <hip/hip_runtime.h>
#include <hip/hip_bf16.h>
#include <math.h>

// B=2 QL=512 KL=8192 D=1024 H=8 HD=128
typedef __attribute__((ext_vector_type(4))) float fx4;
typedef __attribute__((ext_vector_type(4))) short sx4;
typedef __attribute__((ext_vector_type(8))) short sx8;
typedef unsigned long long u64;

#define MFMA16(a, b, c) __builtin_amdgcn_mfma_f32_16x16x16bf16_1k(a, b, c, 0, 0, 0)
#define MFMA32(a, b, c) __builtin_amdgcn_mfma_f32_16x16x32_bf16(a, b, c, 0, 0, 0)

__device__ __forceinline__ unsigned short f2bf(float f) {
  unsigned int u = __float_as_uint(f);
  return (unsigned short)((u + 0x7fffu + ((u >> 16) & 1u)) >> 16);  // RNE
}

// packed f32x2 -> bf16x2 (RNE)
__device__ __forceinline__ unsigned cvtpk(float lo, float hi) {
  unsigned r;
  asm("v_cvt_pk_bf16_f32 %0, %1, %2" : "=v"(r) : "v"(lo), "v"(hi));
  return r;
}

// async global->LDS, 16B per lane; LDS dest is wave-uniform base + lane*16
typedef const __attribute__((address_space(1))) char* gc1p;
typedef __attribute__((address_space(3))) char* lc3p;
__device__ __forceinline__ void glds16(const void* g, const void* lds_uniform) {
  gc1p gp = (gc1p)(unsigned long long)(uintptr_t)g;
  lc3p lp = (lc3p)(unsigned)__builtin_amdgcn_readfirstlane((int)(unsigned)(uintptr_t)lds_uniform);
  __builtin_amdgcn_global_load_lds(gp, lp, 16, 0, 0);
}

// ---------------- prep (slim): weights f32->bf16 only ------------------------
// 256 blocks: Wq,Wk,Wv,Wf (64 blocks each, 16384 elems/block)
__global__ __launch_bounds__(256) void k_prep(
    const float* __restrict__ Wq, const float* __restrict__ Wk,
    const float* __restrict__ Wv, const float* __restrict__ Wf, short* cwq,
    short* cwk, short* cwv, short* cwf) {
  const int bx = blockIdx.x;
  const int t = threadIdx.x;
  const int seg = bx >> 6;
  const float* s = seg == 0 ? Wq : seg == 1 ? Wk : seg == 2 ? Wv : Wf;
  short* d = seg == 0 ? cwq : seg == 1 ? cwk : seg == 2 ? cwv : cwf;
  const size_t base = (size_t)(bx & 63) * 16384;
#pragma unroll
  for (int it = 0; it < 4; it++) {
    const size_t i = base + (size_t)it * 4096 + (size_t)t * 16;
    const fx4 a0 = *(const fx4*)(s + i);
    const fx4 a1 = *(const fx4*)(s + i + 4);
    const fx4 a2 = *(const fx4*)(s + i + 8);
    const fx4 a3 = *(const fx4*)(s + i + 12);
    sx8 o0, o1;
    o0[0] = (short)f2bf(a0[0]); o0[1] = (short)f2bf(a0[1]);
    o0[2] = (short)f2bf(a0[2]); o0[3] = (short)f2bf(a0[3]);
    o0[4] = (short)f2bf(a1[0]); o0[5] = (short)f2bf(a1[1]);
    o0[6] = (short)f2bf(a1[2]); o0[7] = (short)f2bf(a1[3]);
    o1[0] = (short)f2bf(a2[0]); o1[1] = (short)f2bf(a2[1]);
    o1[2] = (short)f2bf(a2[2]); o1[3] = (short)f2bf(a2[3]);
    o1[4] = (short)f2bf(a3[0]); o1[5] = (short)f2bf(a3[1]);
    o1[6] = (short)f2bf(a3[2]); o1[7] = (short)f2bf(a3[3]);
    *(sx8*)(d + i) = o0;
    *(sx8*)(d + i + 8) = o1;
  }
}

// ---------------- pipelined AF32 GEMM: C = alpha*(A_f32[M,1024] @ B^T + b) ---
// Counted-vmcnt schedule (T4), K=1024 fixed, fully unrolled 16 steps.
// Per iter t: issue B(t+1) glds -> [SB(0)] -> issue A(t+2) f32 loads ->
// [SB(0)] -> MFMA(t) -> cvt+ds_write A(t+1) (compiler auto-drains A(t+1))
// -> vmcnt(8|4) lgkmcnt(0) s_barrier (drains B(t+1), keeps A(t+2) flying).
// A-loads get ~2 compute phases of cover; nothing drains to 0 mid-loop.
template <int MODE, int MT>
__device__ __forceinline__ void gemm_pipe(short* sA, short* sB,
                                          const float* __restrict__ Af,
                                          const short* __restrict__ Bw,
                                          const float* __restrict__ bias,
                                          void* __restrict__ Cptr, int M, int N,
                                          float alpha, int bx) {
  constexpr int K = 1024;
  constexpr int NT = 16;
  const int tid = threadIdx.x;
  const int lane = tid & 63;
  const int w = tid >> 6;
  const int quad = lane >> 4;
  const int l16 = lane & 15;
  const int x7 = l16 & 7;
  int m0, n0;
  if (M >= 8192) {
    const int ml = bx & 7, nn = (bx >> 3) & 7, mh = bx >> 6;
    m0 = (mh * 8 + ml) * MT;
    n0 = nn << 7;
  } else {
    const int ntile = N >> 7;
    n0 = (bx % ntile) << 7;
    m0 = (bx / ntile) * MT;
  }
  constexpr int NI = (MT == 128) ? 4 : 2;
  constexpr int NJ = (MT == 128) ? 4 : 2;
  const int wm = (MT == 128) ? ((w >> 1) << 6) : 0;
  const int wn = (MT == 128) ? ((w & 1) << 6) : (w << 5);
  const fx4 fzero = {0.f, 0.f, 0.f, 0.f};
  fx4 acc[4][NI];
#pragma unroll
  for (int i = 0; i < 4; i++)
#pragma unroll
    for (int j = 0; j < NI; j++) acc[i][j] = fzero;

  const int srow = lane >> 3;
  const int scb = lane & 7;
  fx4 ra[2][NJ][2];

  auto ISSUE_B = [&](int t) {  // stage B(t) -> sB[t&1]
#pragma unroll
    for (int j = 0; j < 4; j++) {
      const int row = w * 32 + j * 8 + srow;
      const int cb = scb ^ (row & 7);
      glds16(Bw + (size_t)(n0 + row) * K + t * 64 + cb * 8,
             &sB[(t & 1) * 8192 + (w * 32 + j * 8) * 64]);
    }
  };
  auto ISSUE_A = [&](int t, int slot) {  // load A(t) f32 -> ra[slot]
#pragma unroll
    for (int j = 0; j < NJ; j++) {
      const int rbase = (MT == 128) ? (w * 32 + j * 8) : (j * 32 + w * 8);
      const int row = rbase + srow;
      const int cb = scb ^ (row & 7);
      const float* src = Af + (size_t)(m0 + row) * K + t * 64 + cb * 8;
      ra[slot][j][0] = *(const fx4*)src;
      ra[slot][j][1] = *(const fx4*)(src + 4);
    }
  };
  auto CVT_A = [&](int t, int slot) {  // cvt ra[slot] -> sA[t&1]
#pragma unroll
    for (int j = 0; j < NJ; j++) {
      const int rbase = (MT == 128) ? (w * 32 + j * 8) : (j * 32 + w * 8);
      sx8 o;
      unsigned* ou = (unsigned*)&o;
      ou[0] = cvtpk(ra[slot][j][0][0], ra[slot][j][0][1]);
      ou[1] = cvtpk(ra[slot][j][0][2], ra[slot][j][0][3]);
      ou[2] = cvtpk(ra[slot][j][1][0], ra[slot][j][1][1]);
      ou[3] = cvtpk(ra[slot][j][1][2], ra[slot][j][1][3]);
      *(sx8*)(&sA[(t & 1) * 8192 + rbase * 64 + lane * 8]) = o;
    }
  };
  auto COMPUTE = [&](int t) {
    const short* pA = sA + (t & 1) * 8192;
    const short* pB = sB + (t & 1) * 8192;
#pragma unroll
    for (int kc = 0; kc < 2; kc++) {
      const int cbp = ((kc * 4 + quad) ^ x7) * 8;
      sx8 fa[4], fb[NI];
#pragma unroll
      for (int i = 0; i < 4; i++)
        fa[i] = *(const sx8*)(&pA[(wm + i * 16 + l16) * 64 + cbp]);
#pragma unroll
      for (int i = 0; i < NI; i++)
        fb[i] = *(const sx8*)(&pB[(wn + i * 16 + l16) * 64 + cbp]);
#pragma unroll
      for (int mi = 0; mi < 4; mi++)
#pragma unroll
        for (int ni = 0; ni < NI; ni++)
          acc[mi][ni] = MFMA32(fa[mi], fb[ni], acc[mi][ni]);
    }
  };

  // ---- prologue: B(0), A(0), B(1), A(1) pinned in order; cvt A(0) ----
  ISSUE_B(0);
  __builtin_amdgcn_sched_barrier(0);
  ISSUE_A(0, 0);
  __builtin_amdgcn_sched_barrier(0);
  ISSUE_B(1);
  __builtin_amdgcn_sched_barrier(0);
  ISSUE_A(1, 1);
  __builtin_amdgcn_sched_barrier(0);
  CVT_A(0, 0);  // auto vmcnt drains A(0) and (pinned order) B(0)
  asm volatile("s_waitcnt lgkmcnt(0)\n\ts_barrier" ::: "memory");

#pragma unroll
  for (int t = 0; t < NT; ++t) {
    if (t + 1 < NT) ISSUE_B(t + 1);
    __builtin_amdgcn_sched_barrier(0);
    if (t + 2 < NT) ISSUE_A(t + 2, t & 1);
    __builtin_amdgcn_sched_barrier(0);
    COMPUTE(t);
    if (t + 1 < NT) CVT_A(t + 1, (t + 1) & 1);
    if (t + 2 < NT) {
      // keep A(t+2) (8 or 4 loads) in flight; drain B(t+1)
      if (MT == 128)
        asm volatile("s_waitcnt vmcnt(8) lgkmcnt(0)\n\ts_barrier" ::: "memory");
      else
        asm volatile("s_waitcnt vmcnt(4) lgkmcnt(0)\n\ts_barrier" ::: "memory");
    } else if (t + 1 < NT) {
      asm volatile("s_waitcnt vmcnt(0) lgkmcnt(0)\n\ts_barrier" ::: "memory");
    }
  }
  // epilogue: C/D layout col=lane&15, row=quad*4+reg
#pragma unroll
  for (int ni = 0; ni < NI; ni++) {
    const int col = n0 + wn + ni * 16 + l16;
    const float bval = bias[col];
    if (MODE == 2) {
#pragma unroll
      for (int mi = 0; mi < 4; mi++) {
        const int rowb = m0 + wm + mi * 16 + quad * 4;
        const int bb = rowb >> 13;
        const int kl = (rowb & 8191) ^ ((col & 8) ? 4 : 0);
        sx4 pkv;
#pragma unroll
        for (int r = 0; r < 4; r++) pkv[r] = (short)f2bf(acc[mi][ni][r] + bval);
        *(sx4*)((unsigned short*)Cptr + ((size_t)bb * 1024 + col) * 8192 + kl) = pkv;
      }
    } else {
#pragma unroll
      for (int mi = 0; mi < 4; mi++)
#pragma unroll
        for (int r = 0; r < 4; r++) {
          const int row = m0 + wm + mi * 16 + quad * 4 + r;
          const float v = (acc[mi][ni][r] + bval) * alpha;
          ((unsigned short*)Cptr)[(size_t)row * N + col] = f2bf(v);
        }
    }
  }
}

// ---------------- bf16-A GEMM body (round-4 dbuf) for out-projection ---------
__device__ __forceinline__ void gemm_out_body(short* sA, short* sB,
                                              const short* __restrict__ A,
                                              const short* __restrict__ Bw,
                                              const float* __restrict__ bias,
                                              float* __restrict__ Cptr, int N,
                                              int K, int bx) {
  constexpr int MT = 64;
  const int tid = threadIdx.x;
  const int lane = tid & 63;
  const int w = tid >> 6;
  const int quad = lane >> 4;
  const int l16 = lane & 15;
  const int x7 = l16 & 7;
  const int ntile = N >> 7;
  const int n0 = (bx % ntile) << 7;
  const int m0 = (bx / ntile) * MT;
  constexpr int NI = 2;
  const int wm = 0;
  const int wn = w << 5;
  const fx4 fzero = {0.f, 0.f, 0.f, 0.f};
  fx4 acc[4][NI];
#pragma unroll
  for (int i = 0; i < 4; i++)
#pragma unroll
    for (int j = 0; j < NI; j++) acc[i][j] = fzero;
  const int srow = lane >> 3;
  const int scb = lane & 7;

#pragma unroll
  for (int j = 0; j < 2; j++) {
    const int rbase = j * 32 + w * 8;
    const int row = rbase + srow;
    const int cb = scb ^ (row & 7);
    glds16(A + (size_t)(m0 + row) * K + cb * 8, &sA[rbase * 64]);
  }
#pragma unroll
  for (int j = 0; j < 4; j++) {
    const int row = w * 32 + j * 8 + srow;
    const int cb = scb ^ (row & 7);
    glds16(Bw + (size_t)(n0 + row) * K + cb * 8, &sB[(w * 32 + j * 8) * 64]);
  }
  __syncthreads();

  int buf = 0;
  for (int k0 = 0; k0 < K; k0 += 64) {
    const int nb = buf ^ 1;
    if (k0 + 64 < K) {
#pragma unroll
      for (int j = 0; j < 4; j++) {
        const int row = w * 32 + j * 8 + srow;
        const int cb = scb ^ (row & 7);
        glds16(Bw + (size_t)(n0 + row) * K + (k0 + 64) + cb * 8,
               &sB[nb * 8192 + (w * 32 + j * 8) * 64]);
      }
#pragma unroll
      for (int j = 0; j < 2; j++) {
        const int rbase = j * 32 + w * 8;
        const int row = rbase + srow;
        const int cb = scb ^ (row & 7);
        glds16(A + (size_t)(m0 + row) * K + (k0 + 64) + cb * 8,
               &sA[nb * 8192 + rbase * 64]);
      }
    }
    const short* pA = sA + buf * 8192;
    const short* pB = sB + buf * 8192;
#pragma unroll
    for (int kc = 0; kc < 2; kc++) {
      const int cbp = ((kc * 4 + quad) ^ x7) * 8;
      sx8 fa[4], fb[NI];
#pragma unroll
      for (int i = 0; i < 4; i++)
        fa[i] = *(const sx8*)(&pA[(wm + i * 16 + l16) * 64 + cbp]);
#pragma unroll
      for (int i = 0; i < NI; i++)
        fb[i] = *(const sx8*)(&pB[(wn + i * 16 + l16) * 64 + cbp]);
#pragma unroll
      for (int mi = 0; mi < 4; mi++)
#pragma unroll
        for (int ni = 0; ni < NI; ni++)
          acc[mi][ni] = MFMA32(fa[mi], fb[ni], acc[mi][ni]);
    }
    __syncthreads();
    buf = nb;
  }
#pragma unroll
  for (int ni = 0; ni < NI; ni++) {
    const int col = n0 + wn + ni * 16 + l16;
    const float bval = bias[col];
#pragma unroll
    for (int mi = 0; mi < 4; mi++)
#pragma unroll
      for (int r = 0; r < 4; r++) {
        const int row = m0 + wm + mi * 16 + quad * 4 + r;
        Cptr[(size_t)row * N + col] = acc[mi][ni][r] + bval;
      }
  }
}

// ---------------- merged projections + mask pack -----------------------------
// grid 4224: [0,1024) K-proj, [1024,2048) V-proj, [2048,2176) Q-proj,
// [2176,4224) mask pack (4 rows/block) — fills the tail passes.
__global__ __launch_bounds__(256, 2) void k_proj(
    const float* __restrict__ ink, const short* __restrict__ cwk,
    const float* __restrict__ bk, short* __restrict__ Kp,
    const float* __restrict__ inv, const short* __restrict__ cwv,
    const float* __restrict__ bv, short* __restrict__ Vt,
    const float* __restrict__ inq, const short* __restrict__ cwq,
    const float* __restrict__ bq, short* __restrict__ Qp, float alpha_q,
    const int* __restrict__ mask, u64* __restrict__ mb) {
  __shared__ __align__(16) short smem[32768];  // 64 KB
  const int bx = blockIdx.x;
  if (bx >= 2176) {  // mask pack
    unsigned char(*nib)[256] = (unsigned char(*)[256])smem;
    const int t = threadIdx.x;
    const int mrow0 = (bx - 2176) * 4;
#pragma unroll
    for (int j = 0; j < 4; j++) {
      const int4 m = *(const int4*)(mask + (size_t)(mrow0 + j) * 1024 + t * 4);
      nib[j][t] = (unsigned char)((m.x != 0) | ((m.y != 0) << 1) |
                                  ((m.z != 0) << 2) | ((m.w != 0) << 3));
    }
    __syncthreads();
    if (t < 64) {
      const int j = t >> 4, i = t & 15;
      u64 wv = 0;
#pragma unroll
      for (int k = 0; k < 16; k++)
        wv |= (u64)(nib[j][i * 16 + k] & 0xF) << (4 * k);
      mb[(size_t)(mrow0 + j) * 16 + i] = wv;
    }
    return;
  }
  if (bx < 1024)
    gemm_pipe<0, 128>(smem, smem + 16384, ink, cwk, bk, Kp, 16384, 1024, 1.f,
                      bx);
  else if (bx < 2048)
    gemm_pipe<2, 128>(smem, smem + 16384, inv, cwv, bv, Vt, 16384, 1024, 1.f,
                      bx - 1024);
  else
    gemm_pipe<0, 64>(smem, smem + 16384, inq, cwq, bq, Qp, 1024, 1024, alpha_q,
                     bx - 2048);
}

// out-projection (A = bf16 summed): grid 128
__global__ __launch_bounds__(256) void k_gemm_out(const short* __restrict__ summed,
                                                  const short* __restrict__ cwf,
                                                  const float* __restrict__ bf,
                                                  float* __restrict__ out) {
  __shared__ __align__(16) short smem[32768];
  gemm_out_body(smem, smem + 16384, summed, cwf, bf, out, 1024, 1024,
                blockIdx.x);
}

// ---------------- flash attention (S^T trick, no-max softmax) ----------------
// grid 1024, XCD-swizzled: x = (g&7) + 8*(qt + 8*(g>>3)), g=(b*8+h)*8+s.
__global__ __launch_bounds__(256, 4) void k_attn(const short* __restrict__ Qp,
                                                 const short* __restrict__ Kp,
                                                 const short* __restrict__ Vt,
                                                 const u64* __restrict__ mb,
                                                 float* __restrict__ ml,
                                                 float* __restrict__ Op) {
  __shared__ __align__(16) short sK[8192];  // 64 keys x 128 d (256B rows, swizzled)
  __shared__ __align__(16) short sV[8192];  // 128 d x 64 keys (128B rows, swizzled)
  const int x = blockIdx.x;
  const int gl = x & 7;
  const int qt = (x >> 3) & 7;
  const int gh = x >> 6;
  const int g = gh * 8 + gl;  // 0..127
  const int s = g & 7;
  const int h = (g >> 3) & 7;
  const int b = g >> 6;
  const int li = ((b * 8 + h) * 8 + qt) * 8 + s;  // logical index for ml/Op
  const int t = threadIdx.x;
  const int lane = t & 63;
  const int w = t >> 6;
  const int quad = lane >> 4;
  const int l16 = lane & 15;
  const int x7 = l16 & 7;
  const int q0 = qt << 6;
  const fx4 fzero = {0.f, 0.f, 0.f, 0.f};

  const short* qbase = Qp + (size_t)(b * 512 + q0 + w * 16 + l16) * 1024 + h * 128;
  sx8 aq[4];
#pragma unroll
  for (int kc = 0; kc < 4; kc++) aq[kc] = *(const sx8*)(qbase + kc * 32 + quad * 8);

  fx4 Ot[8];
#pragma unroll
  for (int d = 0; d < 8; d++) Ot[d] = fzero;
  float lsum = 0.f;

  const short* kbase = Kp + (size_t)(b * 8192 + s * 1024) * 1024 + h * 128;
  const short* vbase = Vt + (size_t)(b * 1024 + h * 128) * 8192 + s * 1024;
  const u64* wdp = mb + (size_t)(b * 512 + q0 + w * 16 + l16) * 128 + s * 16;
  const int srow4 = lane >> 4, scb16 = lane & 15;
  const int srow8 = lane >> 3, scb8 = lane & 7;
  const int h4 = ((quad & 1) ^ ((l16 >> 3) & 1)) * 4;  // 8B-half parity (bank spread)

  for (int kt = 0; kt < 16; kt++) {
    __syncthreads();
#pragma unroll
    for (int j = 0; j < 4; j++) {  // K tile: 4 rows/issue
      const int row = (w * 4 + j) * 4 + srow4;
      const int cb = scb16 ^ (row & 7);
      glds16(kbase + (size_t)(kt * 64 + row) * 1024 + cb * 8, &sK[(w * 4 + j) * 512]);
    }
#pragma unroll
    for (int j = 0; j < 4; j++) {  // V^T tile: 8 rows/issue
      const int row = (w * 4 + j) * 8 + srow8;
      const int cb = scb8 ^ (row & 7);
      glds16(vbase + (size_t)row * 8192 + kt * 64 + cb * 8, &sV[(w * 4 + j) * 512]);
    }
    const u64 wd = wdp[kt];
    __syncthreads();
    const unsigned lo = (unsigned)wd, hi = (unsigned)(wd >> 32);
    sx4 pk[4];
#pragma unroll
    for (int nt = 0; nt < 4; nt++) {
      fx4 a = fzero;
      __builtin_amdgcn_s_setprio(1);
#pragma unroll
      for (int kc = 0; kc < 4; kc++) {
        const sx8 kf = *(const sx8*)(&sK[(nt * 16 + l16) * 128 + ((kc * 4 + quad) ^ x7) * 8]);
        a = MFMA32(kf, aq[kc], a);  // S^T: row=key, col=q
      }
      __builtin_amdgcn_s_setprio(0);
      const unsigned bits = (nt & 2) ? hi : lo;
      const int sh = (nt & 1) * 16 + quad * 4;
      float pv[4];
#pragma unroll
      for (int r = 0; r < 4; r++) {
        const float e = __builtin_amdgcn_exp2f(a[r]);  // scale*log2e folded into Qp
        pv[r] = ((bits >> (sh + r)) & 1u) ? e : 0.f;
        lsum += pv[r];
      }
      sx4 pko;
      ((unsigned*)&pko)[0] = __builtin_amdgcn_perm(
          __float_as_uint(pv[1]) + 0x8000u, __float_as_uint(pv[0]) + 0x8000u, 0x07060302u);
      ((unsigned*)&pko)[1] = __builtin_amdgcn_perm(
          __float_as_uint(pv[3]) + 0x8000u, __float_as_uint(pv[2]) + 0x8000u, 0x07060302u);
      pk[nt] = pko;
    }
    __builtin_amdgcn_s_setprio(1);
#pragma unroll
    for (int dt = 0; dt < 8; dt++) {
      fx4 o = Ot[dt];
#pragma unroll
      for (int nt = 0; nt < 4; nt++) {
        const int cb = (2 * nt + (quad >> 1)) ^ x7;
        const sx4 vf = *(const sx4*)(&sV[(dt * 16 + l16) * 64 + cb * 8 + h4]);
        o = MFMA16(vf, pk[nt], o);  // O^T: row=d, col=q
      }
      Ot[dt] = o;
    }
    __builtin_amdgcn_s_setprio(0);
  }
  lsum += __shfl_xor(lsum, 16, 64);
  lsum += __shfl_xor(lsum, 32, 64);
  if (lane < 16) ml[(size_t)li * 64 + w * 16 + l16] = lsum;
  float* ob = Op + (size_t)li * 8192 + (w * 16 + l16) * 128 + quad * 4;
#pragma unroll
  for (int dt = 0; dt < 8; dt++) *(fx4*)(ob + dt * 16) = Ot[dt];
}

// ---------------- combine 8 KL-split partials -> summed bf16 -----------------
// grid 256: each block does one (b,h,qt) x one 64-wide d-half
__global__ __launch_bounds__(256) void k_combine(const float* __restrict__ ml,
                                                 const float* __restrict__ Op,
                                                 short* __restrict__ summed) {
  const int bx = blockIdx.x;
  const int xc = bx >> 1;        // qt + 8*h + 64*b
  const int dh = (bx & 1) * 64;  // d-half
  const int qt = xc & 7;
  const int h = (xc >> 3) & 7;
  const int b = xc >> 6;
  const int t = threadIdx.x;
  const int row = t >> 2;
  const int dg = dh + (t & 3) * 16;
  float L = 0.f;
#pragma unroll
  for (int s = 0; s < 8; s++) L += ml[(size_t)(xc * 8 + s) * 64 + row];
  float o[16];
#pragma unroll
  for (int i = 0; i < 16; i++) o[i] = 0.f;
  if (L != 0.f) {
#pragma unroll
    for (int s = 0; s < 8; s++) {
      const float* src = Op + (size_t)(xc * 8 + s) * 8192 + row * 128 + dg;
#pragma unroll
      for (int i = 0; i < 4; i++) {
        const fx4 v = *(const fx4*)(src + i * 4);
        o[i * 4 + 0] += v[0]; o[i * 4 + 1] += v[1];
        o[i * 4 + 2] += v[2]; o[i * 4 + 3] += v[3];
      }
    }
    const float inv = 1.f / L;
#pragma unroll
    for (int i = 0; i < 16; i++) o[i] *= inv;
  }
  short* dst = summed + (size_t)(b * 512 + qt * 64 + row) * 1024 + h * 128 + dg;
#pragma unroll
  for (int i = 0; i < 2; i++) {
    sx8 pkv;
#pragma unroll
    for (int j = 0; j < 8; j++) pkv[j] = (short)f2bf(o[i * 8 + j]);
    *(sx8*)(dst + i * 8) = pkv;
  }
}

// ---------------- host ------------------------------------------------------
extern "C" void kernel_launch(void* const* d_in, const int* in_sizes, int n_in,
                              void* d_out, int out_size, void* d_ws, size_t ws_size,
                              hipStream_t stream) {
  (void)in_sizes; (void)n_in; (void)out_size; (void)ws_size;
  const float* inq = (const float*)d_in[0];
  const float* ink = (const float*)d_in[1];
  const float* inv = (const float*)d_in[2];
  const int* mask = (const int*)d_in[3];
  const float* Wq = (const float*)d_in[4];
  const float* bq = (const float*)d_in[5];
  const float* Wk = (const float*)d_in[6];
  const float* bk = (const float*)d_in[7];
  const float* Wv = (const float*)d_in[8];
  const float* bv = (const float*)d_in[9];
  const float* Wf = (const float*)d_in[10];
  const float* bf = (const float*)d_in[11];

  char* ws = (char*)d_ws;
  short* Vt = (short*)(ws + 0);            // 33.5MB bf16
  short* Kp = (short*)(ws + 33554432);     // 33.5MB bf16
  float* Op = (float*)(ws + 67108864);     // 33.5MB f32 attn partials
  short* cwq = (short*)(ws + 102760448);   // 2MB each
  short* cwk = (short*)(ws + 104857600);
  short* cwv = (short*)(ws + 106954752);
  short* cwf = (short*)(ws + 109051904);
  short* Qp = (short*)(ws + 111149056);
  short* summed = (short*)(ws + 113246208);
  u64* mb = (u64*)(ws + 115343360);
  float* ml = (float*)(ws + 116391936);

  const float alpha_q = 0.12751757f;  // (1/sqrt(128)) * log2(e)

  k_prep<<<256, 256, 0, stream>>>(Wq, Wk, Wv, Wf, cwq, cwk, cwv, cwf);
  k_proj<<<4224, 256, 0, stream>>>(ink, cwk, bk, Kp, inv, cwv, bv, Vt, inq, cwq,
                                   bq, Qp, alpha_q, mask, mb);
  k_attn<<<1024, 256, 0, stream>>>(Qp, Kp, Vt, mb, ml, Op);
  k_combine<<<256, 256, 0, stream>>>(ml, Op, summed);
  k_gemm_out<<<128, 256, 0, stream>>>(summed, cwf, bf, (float*)d_out);
}